// Round 10
// baseline (582.774 us; speedup 1.0000x reference)
//
#include <hip/hip_runtime.h>
#include <stdint.h>

#define NB 32
#define NS 40
#define NT 60
#define NH 256
#define NF 64
#define NDIN 320
#define NG 1024
#define NSB 1280
#define NOUT 128

typedef __bf16 bf16x8 __attribute__((ext_vector_type(8)));
typedef float f32x4 __attribute__((ext_vector_type(4)));
typedef uint32_t u32x4 __attribute__((ext_vector_type(4)));

union bfrag { bf16x8 v; uint16_t u[8]; uint4 q; uint64_t d[2]; };
union f2arr { float2 v; float a[2]; };

__device__ __forceinline__ uint16_t f2bf(float f) {
  uint32_t u = __float_as_uint(f);
  u += 0x7fffu + ((u >> 16) & 1u);
  return (uint16_t)(u >> 16);
}
__device__ __forceinline__ float bf2f(uint16_t h) {
  return __uint_as_float(((uint32_t)h) << 16);
}
__device__ __forceinline__ float sig_fast(float x) { return 1.0f / (1.0f + __expf(-x)); }
__device__ __forceinline__ float tanh_fast(float x) {
  x = fminf(fmaxf(x, -15.0f), 15.0f);
  float t = __expf(2.0f * x);
  return (t - 1.0f) / (t + 1.0f);
}
__device__ __forceinline__ uint32_t ld_agent_u32(const uint32_t* p) {
  return __hip_atomic_load(p, __ATOMIC_RELAXED, __HIP_MEMORY_SCOPE_AGENT);
}

// ---------------- mask dtype detector: 0=int32, 1=bytes(bool), 2=float32 ----
__global__ void k_detect(const uint32_t* __restrict__ xm, int* __restrict__ flag) {
  __shared__ int s_notint, s_notflt;
  if (threadIdx.x == 0) { s_notint = 0; s_notflt = 0; }
  __syncthreads();
  int notint = 0, notflt = 0;
  for (int i = threadIdx.x; i < 19200; i += 256) {   // 76800B: safe all dtypes
    uint32_t v = xm[i];
    if (v > 1u) notint = 1;
    if (v != 0u && v != 0x3f800000u) notflt = 1;
  }
  if (notint) atomicOr(&s_notint, 1);
  if (notflt) atomicOr(&s_notflt, 1);
  __syncthreads();
  if (threadIdx.x == 0) {
    int f;
    if (!s_notint) f = 0;
    else if (!s_notflt) f = 2;
    else f = 1;
    *flag = f;
  }
}

// ------- merged: blocks [0,1280) attention pooling; [1280,2560) wih prep ----
__global__ __launch_bounds__(256) void k_attn_prep(
    const int* __restrict__ x, const void* __restrict__ xmask,
    const float* __restrict__ xfeat, const int* __restrict__ slen,
    const float* __restrict__ emb, const float* __restrict__ attn_w,
    uint16_t* __restrict__ Xb, const int* __restrict__ flagp,
    const float* __restrict__ wf, const float* __restrict__ wb,
    uint16_t* __restrict__ outw)
{
  int tid = threadIdx.x;
  if (blockIdx.x >= 1280) {              // ---- wih -> hi/lo bf16 planes ----
    const int n = NG * NDIN;
    for (int idx = (blockIdx.x - 1280) * 256 + tid; idx < 2 * n; idx += 1280 * 256) {
      float v = (idx < n) ? wf[idx] : wb[idx - n];
      uint16_t hi = f2bf(v);
      outw[idx] = hi;
      outw[2 * n + idx] = f2bf(v - bf2f(hi));
    }
    return;
  }
  int bs = blockIdx.x;
  int b = bs / NS, s = bs % NS;
  uint16_t* Xh = Xb + (size_t)(s * NB + b) * NDIN;
  uint16_t* Xl = Xh + (size_t)NSB * NDIN;
  int len = slen[b];
  if (s >= len) {
    for (int i = tid; i < NDIN; i += 256) { Xh[i] = 0; Xl[i] = 0; }
    return;
  }
  __shared__ __attribute__((aligned(16))) float sw[NH];
  __shared__ float salpha[NT];
  __shared__ int sidx[NT];
  __shared__ unsigned char svalid[NT];
  __shared__ __attribute__((aligned(16))) uint16_t es[NT][NH];
  sw[tid] = attn_w[tid];
  int flag = *flagp;
  if (tid < NT) {
    int mi = bs * NT + tid;
    sidx[tid] = x[mi];
    int mv;
    if (flag == 1)      mv = ((const unsigned char*)xmask)[mi];
    else if (flag == 2) mv = (((const float*)xmask)[mi] != 0.0f) ? 1 : 0;
    else                mv = ((const int*)xmask)[mi];
    svalid[tid] = (mv == 0) ? 1 : 0;
  }
  __syncthreads();
  int wave = tid >> 6, lane = tid & 63;
  for (int t = wave; t < NT; t += 4) {
    float d = 0.0f;
    if (svalid[t]) {
      const float* er = emb + (size_t)sidx[t] * NH;
      float4 e4 = ((const float4*)er)[lane];
      float4 w4 = ((const float4*)sw)[lane];
      uint16_t* ed = &es[t][lane * 4];
      ed[0] = f2bf(e4.x); ed[1] = f2bf(e4.y); ed[2] = f2bf(e4.z); ed[3] = f2bf(e4.w);
      d = e4.x * w4.x + e4.y * w4.y + e4.z * w4.z + e4.w * w4.w;
      #pragma unroll
      for (int o = 32; o > 0; o >>= 1) d += __shfl_down(d, o);
    }
    if (lane == 0) salpha[t] = d;
  }
  __syncthreads();
  if (tid < 64) {                        // wave-parallel softmax over <=60 tokens
    int valid = (tid < NT) && svalid[tid];
    float v = valid ? salpha[tid] : -1e30f;
    float m = v;
    #pragma unroll
    for (int o = 32; o > 0; o >>= 1) m = fmaxf(m, __shfl_xor(m, o));
    float e = valid ? expf(v - m) : 0.0f;
    float ssum = e;
    #pragma unroll
    for (int o = 32; o > 0; o >>= 1) ssum += __shfl_xor(ssum, o);
    if (tid < NT) salpha[tid] = e / ssum;
  }
  __syncthreads();
  float acc = 0.0f;
  for (int t = 0; t < NT; t++) {
    float a = salpha[t];
    if (a != 0.0f) acc += a * bf2f(es[t][tid]);
  }
  {
    uint16_t hi = f2bf(acc);
    Xh[tid] = hi; Xl[tid] = f2bf(acc - bf2f(hi));
  }
  if (tid < NF) {
    float fa = 0.0f;
    const float* fp = xfeat + (size_t)bs * NT * NF + tid;
    for (int t = 0; t < NT; t++) if (svalid[t]) fa += fp[t * NF];
    uint16_t hi = f2bf(fa);
    Xh[NH + tid] = hi; Xl[NH + tid] = f2bf(fa - bf2f(hi));
  }
}

// ------- gbase = X @ wih^T + bih + bhh, hi/lo split operands ----------------
__global__ __launch_bounds__(512) void k_gbase(
    const uint16_t* __restrict__ Xb, const uint16_t* __restrict__ wihb,
    const float* __restrict__ bih_f, const float* __restrict__ bhh_f,
    const float* __restrict__ bih_b, const float* __restrict__ bhh_b,
    float* __restrict__ gbase)
{
  const int n = NG * NDIN;
  int wave = threadIdx.x >> 6, lane = threadIdx.x & 63;
  int job = blockIdx.x * 8 + wave;
  int dir = job / 1280;
  int r = job % 1280;
  int nt = r % 64, ms = r / 64;
  int m0 = ms * 64;
  const uint16_t* Wh = wihb + (size_t)dir * n;
  const uint16_t* Wl = Wh + (size_t)2 * n;
  const uint16_t* Ah = Xb;
  const uint16_t* Al = Xb + (size_t)NSB * NDIN;
  int lrow = lane & 15, lk = (lane >> 4) * 8;
  f32x4 acc0 = {0,0,0,0}, acc1 = acc0, acc2 = acc0, acc3 = acc0;
  for (int kk = 0; kk < 10; kk++) {
    int k0 = kk * 32 + lk;
    bfrag bh, bl, ah0, ah1, ah2, ah3, al0, al1, al2, al3;
    bh.q = *(const uint4*)(Wh + (size_t)(nt * 16 + lrow) * NDIN + k0);
    bl.q = *(const uint4*)(Wl + (size_t)(nt * 16 + lrow) * NDIN + k0);
    ah0.q = *(const uint4*)(Ah + (size_t)(m0 +  0 + lrow) * NDIN + k0);
    ah1.q = *(const uint4*)(Ah + (size_t)(m0 + 16 + lrow) * NDIN + k0);
    ah2.q = *(const uint4*)(Ah + (size_t)(m0 + 32 + lrow) * NDIN + k0);
    ah3.q = *(const uint4*)(Ah + (size_t)(m0 + 48 + lrow) * NDIN + k0);
    al0.q = *(const uint4*)(Al + (size_t)(m0 +  0 + lrow) * NDIN + k0);
    al1.q = *(const uint4*)(Al + (size_t)(m0 + 16 + lrow) * NDIN + k0);
    al2.q = *(const uint4*)(Al + (size_t)(m0 + 32 + lrow) * NDIN + k0);
    al3.q = *(const uint4*)(Al + (size_t)(m0 + 48 + lrow) * NDIN + k0);
    acc0 = __builtin_amdgcn_mfma_f32_16x16x32_bf16(ah0.v, bh.v, acc0, 0, 0, 0);
    acc0 = __builtin_amdgcn_mfma_f32_16x16x32_bf16(ah0.v, bl.v, acc0, 0, 0, 0);
    acc0 = __builtin_amdgcn_mfma_f32_16x16x32_bf16(al0.v, bh.v, acc0, 0, 0, 0);
    acc1 = __builtin_amdgcn_mfma_f32_16x16x32_bf16(ah1.v, bh.v, acc1, 0, 0, 0);
    acc1 = __builtin_amdgcn_mfma_f32_16x16x32_bf16(ah1.v, bl.v, acc1, 0, 0, 0);
    acc1 = __builtin_amdgcn_mfma_f32_16x16x32_bf16(al1.v, bh.v, acc1, 0, 0, 0);
    acc2 = __builtin_amdgcn_mfma_f32_16x16x32_bf16(ah2.v, bh.v, acc2, 0, 0, 0);
    acc2 = __builtin_amdgcn_mfma_f32_16x16x32_bf16(ah2.v, bl.v, acc2, 0, 0, 0);
    acc2 = __builtin_amdgcn_mfma_f32_16x16x32_bf16(al2.v, bh.v, acc2, 0, 0, 0);
    acc3 = __builtin_amdgcn_mfma_f32_16x16x32_bf16(ah3.v, bh.v, acc3, 0, 0, 0);
    acc3 = __builtin_amdgcn_mfma_f32_16x16x32_bf16(ah3.v, bl.v, acc3, 0, 0, 0);
    acc3 = __builtin_amdgcn_mfma_f32_16x16x32_bf16(al3.v, bh.v, acc3, 0, 0, 0);
  }
  int col = nt * 16 + lrow;
  float bias = dir ? (bih_b[col] + bhh_b[col]) : (bih_f[col] + bhh_f[col]);
  float* gb = gbase + (size_t)dir * NSB * NG;
  int rb = (lane >> 4) * 4;
  #pragma unroll
  for (int rr = 0; rr < 4; rr++) {
    gb[(size_t)(m0 +  0 + rb + rr) * NG + col] = acc0[rr] + bias;
    gb[(size_t)(m0 + 16 + rb + rr) * NG + col] = acc1[rr] + bias;
    gb[(size_t)(m0 + 32 + rb + rr) * NG + col] = acc2[rr] + bias;
    gb[(size_t)(m0 + 48 + rb + rr) * NG + col] = acc3[rr] + bias;
  }
}

// ---------------- persistent bidirectional LSTM: 16 blocks ------------------
// R8-proven protocol: tagged 16B granules {tag, hi2, lo2, pad}, single poll
// batch with loads + vmcnt(0) INSIDE one asm block (no un-retired asm outputs
// visible to the compiler). R10 change: thread tid owns granules s=tid*8+q
// (same memory layout; producer/k_final untouched) so the 8 poll loads use
// ONE named address register + offset:16..112 immediates -- no runtime-indexed
// address array (rule #20), fewer VGPRs -- and the LDS scatter is 4x uint4.
__global__ __launch_bounds__(512, 2) void k_lstm(
    const float* __restrict__ whh_f_, const float* __restrict__ whh_b_,
    const float* __restrict__ gbase, const int* __restrict__ slen,
    uint32_t* __restrict__ gr)
{
  int wg = blockIdx.x;
  int dir = wg >> 3, p = wg & 7;
  int u0 = p * 32;
  int tid = threadIdx.x, wave = tid >> 6, lane = tid & 63;
  int lrow = lane & 15, lkb = (lane >> 4) * 8;
  const float* Wr = dir ? whh_b_ : whh_f_;
  const float* gb = gbase + (size_t)dir * NSB * NG;
  uint32_t* grd = gr + (size_t)dir * 2 * NB * 128 * 4;  // [par][batch][unitpair]{4xu32}

  __shared__ __attribute__((aligned(16))) uint16_t hs[2][NB][264];
  __shared__ float tscr[8][32 * 18];

  // W frags hi+lo: wave tile col c -> weight row (c>>2)*256 + u0 + wave*4 + (c&3)
  bfrag wh[8], wl[8];
  {
    int wr = (lrow >> 2) * 256 + u0 + wave * 4 + (lrow & 3);
    const float* wrow = Wr + (size_t)wr * NH;
    #pragma unroll
    for (int kk = 0; kk < 8; kk++) {
      int k0 = kk * 32 + lkb;
      bfrag th, tl;
      #pragma unroll
      for (int e = 0; e < 8; e++) {
        float v0 = wrow[k0 + e];
        uint16_t h0_ = f2bf(v0);
        th.u[e] = h0_; tl.u[e] = f2bf(v0 - bf2f(h0_));
      }
      wh[kk] = th; wl[kk] = tl;
    }
  }
  int beta = lane >> 1;                     // batch owned in pointwise
  int upg = p * 16 + wave * 2 + (lane & 1); // global unitpair owned (2 units)
  int len = slen[beta];
  uint32_t hprev_hi = 0, hprev_lo = 0;
  float c0 = 0.0f, c1 = 0.0f;

  // named parity base addresses (no arrays -> no scratch)
  uint64_t ab0 = (uint64_t)(uintptr_t)grd + (uint64_t)tid * 128;
  uint64_t ab1 = ab0 + (uint64_t)NB * 128 * 16;

  for (int i = 0; i < NS; i++) {
    int t = dir ? (NS - 1 - i) : i;
    // ---- g prefetch (compiler loads; compiler manages waits) ----
    const float* gptr = gb + ((size_t)t * NB + beta) * NG + u0 + wave * 4 + (lane & 1) * 2;
    f2arr g0, g1, g2, g3;
    g0.v = *(const float2*)(gptr);
    g1.v = *(const float2*)(gptr + 256);
    g2.v = *(const float2*)(gptr + 512);
    g3.v = *(const float2*)(gptr + 768);
    // ---- tagged-granule fetch: 8 x 16B sc1 from ONE base, retry ----
    u32x4 v0, v1, v2, v3, v4, v5, v6, v7;
    {
      uint64_t ab = (i & 1) ? ab1 : ab0;
      uint32_t need = (uint32_t)i;
      long spins = 0;
      for (;;) {
        asm volatile(
          "global_load_dwordx4 %0, %8, off sc1\n\t"
          "global_load_dwordx4 %1, %8, off offset:16 sc1\n\t"
          "global_load_dwordx4 %2, %8, off offset:32 sc1\n\t"
          "global_load_dwordx4 %3, %8, off offset:48 sc1\n\t"
          "global_load_dwordx4 %4, %8, off offset:64 sc1\n\t"
          "global_load_dwordx4 %5, %8, off offset:80 sc1\n\t"
          "global_load_dwordx4 %6, %8, off offset:96 sc1\n\t"
          "global_load_dwordx4 %7, %8, off offset:112 sc1\n\t"
          "s_waitcnt vmcnt(0)"
          : "=&v"(v0), "=&v"(v1), "=&v"(v2), "=&v"(v3),
            "=&v"(v4), "=&v"(v5), "=&v"(v6), "=&v"(v7)
          : "v"(ab)
          : "memory");
        if (v0.x >= need && v1.x >= need && v2.x >= need && v3.x >= need &&
            v4.x >= need && v5.x >= need && v6.x >= need && v7.x >= need) break;
        if (++spins > (1L << 16)) break;   // safety: wrong-answer, not hang
      }
    }
    __syncthreads();                       // prev-step hs fully consumed
    // ---- scatter: tid owns granules s=tid*8..tid*8+7 -> bb=tid>>4 (fixed),
    //      up=(tid&15)*8+q -> 16 contiguous u16 per plane = 2x uint4 each ----
    {
      uint4 hiA, hiB, loA, loB;
      hiA.x = v0.y; hiA.y = v1.y; hiA.z = v2.y; hiA.w = v3.y;
      hiB.x = v4.y; hiB.y = v5.y; hiB.z = v6.y; hiB.w = v7.y;
      loA.x = v0.z; loA.y = v1.z; loA.z = v2.z; loA.w = v3.z;
      loB.x = v4.z; loB.y = v5.z; loB.z = v6.z; loB.w = v7.z;
      uint16_t* d0 = &hs[0][tid >> 4][(tid & 15) * 16];
      uint16_t* d1 = &hs[1][tid >> 4][(tid & 15) * 16];
      *(uint4*)(d0) = hiA; *((uint4*)(d0) + 1) = hiB;
      *(uint4*)(d1) = loA; *((uint4*)(d1) + 1) = loB;
    }
    __syncthreads();                       // hs ready
    // ---- recurrent MFMA: acc = Ah*Wh + Ah*Wl + Al*Wh ----
    f32x4 acc0 = {0,0,0,0}, acc1 = acc0;
    #pragma unroll
    for (int kk = 0; kk < 8; kk++) {
      int k0 = kk * 32 + lkb;
      bfrag ah0, ah1, al0, al1;
      ah0.q = *(const uint4*)(&hs[0][lrow][k0]);
      ah1.q = *(const uint4*)(&hs[0][16 + lrow][k0]);
      al0.q = *(const uint4*)(&hs[1][lrow][k0]);
      al1.q = *(const uint4*)(&hs[1][16 + lrow][k0]);
      acc0 = __builtin_amdgcn_mfma_f32_16x16x32_bf16(ah0.v, wh[kk].v, acc0, 0, 0, 0);
      acc0 = __builtin_amdgcn_mfma_f32_16x16x32_bf16(ah0.v, wl[kk].v, acc0, 0, 0, 0);
      acc0 = __builtin_amdgcn_mfma_f32_16x16x32_bf16(al0.v, wh[kk].v, acc0, 0, 0, 0);
      acc1 = __builtin_amdgcn_mfma_f32_16x16x32_bf16(ah1.v, wh[kk].v, acc1, 0, 0, 0);
      acc1 = __builtin_amdgcn_mfma_f32_16x16x32_bf16(ah1.v, wl[kk].v, acc1, 0, 0, 0);
      acc1 = __builtin_amdgcn_mfma_f32_16x16x32_bf16(al1.v, wh[kk].v, acc1, 0, 0, 0);
    }
    // ---- intra-wave transpose (volatile LDS, same-wave ordering) ----
    volatile float* ts = &tscr[wave][0];
    {
      int colT = lane & 15, rb = (lane >> 4) * 4;
      #pragma unroll
      for (int rr = 0; rr < 4; rr++) {
        ts[(rb + rr) * 18 + colT]      = acc0[rr];
        ts[(16 + rb + rr) * 18 + colT] = acc1[rr];
      }
    }
    int e2 = (lane & 1) * 2;
    float gv00 = ts[beta * 18 + 0 + e2],  gv01 = ts[beta * 18 + 1 + e2];
    float gv10 = ts[beta * 18 + 4 + e2],  gv11 = ts[beta * 18 + 5 + e2];
    float gv20 = ts[beta * 18 + 8 + e2],  gv21 = ts[beta * 18 + 9 + e2];
    float gv30 = ts[beta * 18 + 12 + e2], gv31 = ts[beta * 18 + 13 + e2];
    // ---- pointwise (fast math) + tagged publish ----
    {
      int upd = (t < len) ? 1 : 0;
      float gi0 = gv00 + g0.a[0], gi1 = gv01 + g0.a[1];
      float gf0 = gv10 + g1.a[0], gf1 = gv11 + g1.a[1];
      float gg0 = gv20 + g2.a[0], gg1 = gv21 + g2.a[1];
      float go0 = gv30 + g3.a[0], go1 = gv31 + g3.a[1];
      float c2a = sig_fast(gf0) * c0 + sig_fast(gi0) * tanh_fast(gg0);
      float c2b = sig_fast(gf1) * c1 + sig_fast(gi1) * tanh_fast(gg1);
      float h2a = sig_fast(go0) * tanh_fast(c2a);
      float h2b = sig_fast(go1) * tanh_fast(c2b);
      c0 = upd ? c2a : c0;
      c1 = upd ? c2b : c1;
      uint32_t hiw, low;
      if (upd) {
        uint16_t ha = f2bf(h2a), hbb = f2bf(h2b);
        uint16_t la = f2bf(h2a - bf2f(ha)), lb = f2bf(h2b - bf2f(hbb));
        hiw = (uint32_t)ha | ((uint32_t)hbb << 16);
        low = (uint32_t)la | ((uint32_t)lb << 16);
      } else { hiw = hprev_hi; low = hprev_lo; }
      hprev_hi = hiw; hprev_lo = low;
      uint32_t* gout = grd + ((size_t)(((i + 1) & 1) * NB + beta) * 128 + upg) * 4;
      u32x4 pv;
      pv.x = (uint32_t)(i + 1); pv.y = hiw; pv.z = low; pv.w = 0u;
      asm volatile("global_store_dwordx4 %0, %1, off sc1"
                   :: "v"((unsigned long long)(uintptr_t)gout), "v"(pv) : "memory");
    }
  }
}

// ---------------- FC + BatchNorm + ReLU + log_softmax(axis=0) ---------------
__global__ __launch_bounds__(1024) void k_final(
    const uint32_t* __restrict__ gr, const float* __restrict__ fc_w,
    const float* __restrict__ fc_b, const float* __restrict__ gamma_,
    const float* __restrict__ beta_, float* __restrict__ outp)
{
  __shared__ float hid[NB][512];
  __shared__ float ylds[NB][NOUT];
  int tid = threadIdx.x;
  // final h: parity 0 (NS=40 even), granule {tag, hi2, lo2, pad}
  for (int idx = tid; idx < NB * 512; idx += 1024) {
    int bb = idx >> 9, k = idx & 511;
    int bsrc = 2 * (bb & 15) + (k >> 8);
    int hcol = k & 255;
    int dirn = (bb < 16) ? 0 : 1;
    const uint32_t* g = gr + ((size_t)dirn * 2 * NB * 128 + (size_t)bsrc * 128 + (hcol >> 1)) * 4;
    uint32_t hi2 = ld_agent_u32(g + 1);
    uint32_t lo2 = ld_agent_u32(g + 2);
    int sh = (hcol & 1) * 16;
    hid[bb][k] = bf2f((uint16_t)(hi2 >> sh)) + bf2f((uint16_t)(lo2 >> sh));
  }
  __syncthreads();
  int o = tid & 127, b0 = tid >> 7;
  float a0 = 0, a1 = 0, a2 = 0, a3 = 0;
  const float4* wrow = (const float4*)(fc_w + (size_t)o * 512);
  for (int k4 = 0; k4 < 128; k4++) {
    float4 w = wrow[k4];
    float4 h0 = *(const float4*)(&hid[b0][k4 * 4]);
    float4 h1 = *(const float4*)(&hid[b0 + 8][k4 * 4]);
    float4 h2 = *(const float4*)(&hid[b0 + 16][k4 * 4]);
    float4 h3 = *(const float4*)(&hid[b0 + 24][k4 * 4]);
    a0 += w.x * h0.x + w.y * h0.y + w.z * h0.z + w.w * h0.w;
    a1 += w.x * h1.x + w.y * h1.y + w.z * h1.z + w.w * h1.w;
    a2 += w.x * h2.x + w.y * h2.y + w.z * h2.z + w.w * h2.w;
    a3 += w.x * h3.x + w.y * h3.y + w.z * h3.z + w.w * h3.w;
  }
  float bias = fc_b[o];
  ylds[b0][o]      = a0 + bias;
  ylds[b0 + 8][o]  = a1 + bias;
  ylds[b0 + 16][o] = a2 + bias;
  ylds[b0 + 24][o] = a3 + bias;
  __syncthreads();
  if (tid < NOUT) {
    float mu = 0;
    for (int bb = 0; bb < NB; bb++) mu += ylds[bb][tid];
    mu *= (1.0f / NB);
    float var = 0;
    for (int bb = 0; bb < NB; bb++) { float d = ylds[bb][tid] - mu; var += d * d; }
    var *= (1.0f / NB);
    float g = gamma_[tid], be = beta_[tid];
    float inv = 1.0f / sqrtf(var + 1e-5f);
    float ym = -1e30f;
    for (int bb = 0; bb < NB; bb++) {
      float y = g * (ylds[bb][tid] - mu) * inv + be;
      y = fmaxf(y, 0.0f);
      ylds[bb][tid] = y;
      if (y > ym) ym = y;
    }
    float se = 0;
    for (int bb = 0; bb < NB; bb++) se += expf(ylds[bb][tid] - ym);
    float lse = ym + logf(se);
    for (int bb = 0; bb < NB; bb++) outp[bb * NOUT + tid] = ylds[bb][tid] - lse;
  }
}

extern "C" void kernel_launch(void* const* d_in, const int* in_sizes, int n_in,
                              void* d_out, int out_size, void* d_ws, size_t ws_size,
                              hipStream_t stream) {
  (void)in_sizes; (void)n_in; (void)out_size; (void)ws_size;
  const int*   x      = (const int*)  d_in[0];
  const void*  xmask  =               d_in[1];
  const float* xfeat  = (const float*)d_in[2];
  const int*   slen   = (const int*)  d_in[3];
  const float* emb    = (const float*)d_in[6];
  const float* attn_w = (const float*)d_in[7];
  const float* wih_f  = (const float*)d_in[9];
  const float* whh_f  = (const float*)d_in[10];
  const float* bih_f  = (const float*)d_in[11];
  const float* bhh_f  = (const float*)d_in[12];
  const float* wih_b  = (const float*)d_in[13];
  const float* whh_b  = (const float*)d_in[14];
  const float* bih_b  = (const float*)d_in[15];
  const float* bhh_b  = (const float*)d_in[16];
  const float* fc_w   = (const float*)d_in[17];
  const float* fc_b   = (const float*)d_in[18];
  const float* gam    = (const float*)d_in[19];
  const float* bet    = (const float*)d_in[20];

  char* ws = (char*)d_ws;
  int*      flag  = (int*)ws;                        // [0, 4096): mask-dtype flag
  uint32_t* gr    = (uint32_t*)(ws + 4096);          // granules 2dir x 2par x 32x128 x 16B (262,144 B)
  uint16_t* Xb    = (uint16_t*)(ws + 266240);        // 2 planes x 1280x320 bf16 (1,638,400 B)
  uint16_t* wihb  = (uint16_t*)(ws + 1904640);       // 4 planes x 1024x320 bf16 (2,621,440 B)
  float*    gbase = (float*)(ws + 4526080);          // 2x1280x1024 f32 (10,485,760 B)

  hipMemsetAsync(ws, 0, 266240, stream);             // flag + granule tags/data in one shot
  k_detect<<<1, 256, 0, stream>>>((const uint32_t*)xmask, flag);
  k_attn_prep<<<2560, 256, 0, stream>>>(x, xmask, xfeat, slen, emb, attn_w, Xb, flag,
                                        wih_f, wih_b, wihb);
  k_gbase<<<320, 512, 0, stream>>>(Xb, wihb, bih_f, bhh_f, bih_b, bhh_b, gbase);
  k_lstm<<<16, 512, 0, stream>>>(whh_f, whh_b, gbase, slen, gr);
  k_final<<<1, 1024, 0, stream>>>(gr, fc_w, fc_b, gam, bet, (float*)d_out);
}

// Round 11
// 380.972 us; speedup vs baseline: 1.5297x; 1.5297x over previous
//
#include <hip/hip_runtime.h>
#include <stdint.h>

#define NB 32
#define NS 40
#define NT 60
#define NH 256
#define NF 64
#define NDIN 320
#define NG 1024
#define NSB 1280
#define NOUT 128

typedef __bf16 bf16x8 __attribute__((ext_vector_type(8)));
typedef float f32x4 __attribute__((ext_vector_type(4)));
typedef uint32_t u32x4 __attribute__((ext_vector_type(4)));

union bfrag { bf16x8 v; uint16_t u[8]; uint4 q; uint64_t d[2]; };
union f2arr { float2 v; float a[2]; };

__device__ __forceinline__ uint16_t f2bf(float f) {
  uint32_t u = __float_as_uint(f);
  u += 0x7fffu + ((u >> 16) & 1u);
  return (uint16_t)(u >> 16);
}
__device__ __forceinline__ float bf2f(uint16_t h) {
  return __uint_as_float(((uint32_t)h) << 16);
}
__device__ __forceinline__ float sig_fast(float x) { return 1.0f / (1.0f + __expf(-x)); }
__device__ __forceinline__ float tanh_fast(float x) {
  x = fminf(fmaxf(x, -15.0f), 15.0f);
  float t = __expf(2.0f * x);
  return (t - 1.0f) / (t + 1.0f);
}
__device__ __forceinline__ uint32_t ld_agent_u32(const uint32_t* p) {
  return __hip_atomic_load(p, __ATOMIC_RELAXED, __HIP_MEMORY_SCOPE_AGENT);
}

// ---------------- mask dtype detector: 0=int32, 1=bytes(bool), 2=float32 ----
__global__ void k_detect(const uint32_t* __restrict__ xm, int* __restrict__ flag) {
  __shared__ int s_notint, s_notflt;
  if (threadIdx.x == 0) { s_notint = 0; s_notflt = 0; }
  __syncthreads();
  int notint = 0, notflt = 0;
  for (int i = threadIdx.x; i < 19200; i += 256) {   // 76800B: safe all dtypes
    uint32_t v = xm[i];
    if (v > 1u) notint = 1;
    if (v != 0u && v != 0x3f800000u) notflt = 1;
  }
  if (notint) atomicOr(&s_notint, 1);
  if (notflt) atomicOr(&s_notflt, 1);
  __syncthreads();
  if (threadIdx.x == 0) {
    int f;
    if (!s_notint) f = 0;
    else if (!s_notflt) f = 2;
    else f = 1;
    *flag = f;
  }
}

// ------- merged: blocks [0,1280) attention pooling; [1280,2560) wih prep ----
__global__ __launch_bounds__(256) void k_attn_prep(
    const int* __restrict__ x, const void* __restrict__ xmask,
    const float* __restrict__ xfeat, const int* __restrict__ slen,
    const float* __restrict__ emb, const float* __restrict__ attn_w,
    uint16_t* __restrict__ Xb, const int* __restrict__ flagp,
    const float* __restrict__ wf, const float* __restrict__ wb,
    uint16_t* __restrict__ outw)
{
  int tid = threadIdx.x;
  if (blockIdx.x >= 1280) {              // ---- wih -> hi/lo bf16 planes ----
    const int n = NG * NDIN;
    for (int idx = (blockIdx.x - 1280) * 256 + tid; idx < 2 * n; idx += 1280 * 256) {
      float v = (idx < n) ? wf[idx] : wb[idx - n];
      uint16_t hi = f2bf(v);
      outw[idx] = hi;
      outw[2 * n + idx] = f2bf(v - bf2f(hi));
    }
    return;
  }
  int bs = blockIdx.x;
  int b = bs / NS, s = bs % NS;
  uint16_t* Xh = Xb + (size_t)(s * NB + b) * NDIN;
  uint16_t* Xl = Xh + (size_t)NSB * NDIN;
  int len = slen[b];
  if (s >= len) {
    for (int i = tid; i < NDIN; i += 256) { Xh[i] = 0; Xl[i] = 0; }
    return;
  }
  __shared__ __attribute__((aligned(16))) float sw[NH];
  __shared__ float salpha[NT];
  __shared__ int sidx[NT];
  __shared__ unsigned char svalid[NT];
  __shared__ __attribute__((aligned(16))) uint16_t es[NT][NH];
  sw[tid] = attn_w[tid];
  int flag = *flagp;
  if (tid < NT) {
    int mi = bs * NT + tid;
    sidx[tid] = x[mi];
    int mv;
    if (flag == 1)      mv = ((const unsigned char*)xmask)[mi];
    else if (flag == 2) mv = (((const float*)xmask)[mi] != 0.0f) ? 1 : 0;
    else                mv = ((const int*)xmask)[mi];
    svalid[tid] = (mv == 0) ? 1 : 0;
  }
  __syncthreads();
  int wave = tid >> 6, lane = tid & 63;
  for (int t = wave; t < NT; t += 4) {
    float d = 0.0f;
    if (svalid[t]) {
      const float* er = emb + (size_t)sidx[t] * NH;
      float4 e4 = ((const float4*)er)[lane];
      float4 w4 = ((const float4*)sw)[lane];
      uint16_t* ed = &es[t][lane * 4];
      ed[0] = f2bf(e4.x); ed[1] = f2bf(e4.y); ed[2] = f2bf(e4.z); ed[3] = f2bf(e4.w);
      d = e4.x * w4.x + e4.y * w4.y + e4.z * w4.z + e4.w * w4.w;
      #pragma unroll
      for (int o = 32; o > 0; o >>= 1) d += __shfl_down(d, o);
    }
    if (lane == 0) salpha[t] = d;
  }
  __syncthreads();
  if (tid < 64) {                        // wave-parallel softmax over <=60 tokens
    int valid = (tid < NT) && svalid[tid];
    float v = valid ? salpha[tid] : -1e30f;
    float m = v;
    #pragma unroll
    for (int o = 32; o > 0; o >>= 1) m = fmaxf(m, __shfl_xor(m, o));
    float e = valid ? expf(v - m) : 0.0f;
    float ssum = e;
    #pragma unroll
    for (int o = 32; o > 0; o >>= 1) ssum += __shfl_xor(ssum, o);
    if (tid < NT) salpha[tid] = e / ssum;
  }
  __syncthreads();
  float acc = 0.0f;
  for (int t = 0; t < NT; t++) {
    float a = salpha[t];
    if (a != 0.0f) acc += a * bf2f(es[t][tid]);
  }
  {
    uint16_t hi = f2bf(acc);
    Xh[tid] = hi; Xl[tid] = f2bf(acc - bf2f(hi));
  }
  if (tid < NF) {
    float fa = 0.0f;
    const float* fp = xfeat + (size_t)bs * NT * NF + tid;
    for (int t = 0; t < NT; t++) if (svalid[t]) fa += fp[t * NF];
    uint16_t hi = f2bf(fa);
    Xh[NH + tid] = hi; Xl[NH + tid] = f2bf(fa - bf2f(hi));
  }
}

// ------- gbase = X @ wih^T + bih + bhh, hi/lo split operands ----------------
__global__ __launch_bounds__(512) void k_gbase(
    const uint16_t* __restrict__ Xb, const uint16_t* __restrict__ wihb,
    const float* __restrict__ bih_f, const float* __restrict__ bhh_f,
    const float* __restrict__ bih_b, const float* __restrict__ bhh_b,
    float* __restrict__ gbase)
{
  const int n = NG * NDIN;
  int wave = threadIdx.x >> 6, lane = threadIdx.x & 63;
  int job = blockIdx.x * 8 + wave;
  int dir = job / 1280;
  int r = job % 1280;
  int nt = r % 64, ms = r / 64;
  int m0 = ms * 64;
  const uint16_t* Wh = wihb + (size_t)dir * n;
  const uint16_t* Wl = Wh + (size_t)2 * n;
  const uint16_t* Ah = Xb;
  const uint16_t* Al = Xb + (size_t)NSB * NDIN;
  int lrow = lane & 15, lk = (lane >> 4) * 8;
  f32x4 acc0 = {0,0,0,0}, acc1 = acc0, acc2 = acc0, acc3 = acc0;
  for (int kk = 0; kk < 10; kk++) {
    int k0 = kk * 32 + lk;
    bfrag bh, bl, ah0, ah1, ah2, ah3, al0, al1, al2, al3;
    bh.q = *(const uint4*)(Wh + (size_t)(nt * 16 + lrow) * NDIN + k0);
    bl.q = *(const uint4*)(Wl + (size_t)(nt * 16 + lrow) * NDIN + k0);
    ah0.q = *(const uint4*)(Ah + (size_t)(m0 +  0 + lrow) * NDIN + k0);
    ah1.q = *(const uint4*)(Ah + (size_t)(m0 + 16 + lrow) * NDIN + k0);
    ah2.q = *(const uint4*)(Ah + (size_t)(m0 + 32 + lrow) * NDIN + k0);
    ah3.q = *(const uint4*)(Ah + (size_t)(m0 + 48 + lrow) * NDIN + k0);
    al0.q = *(const uint4*)(Al + (size_t)(m0 +  0 + lrow) * NDIN + k0);
    al1.q = *(const uint4*)(Al + (size_t)(m0 + 16 + lrow) * NDIN + k0);
    al2.q = *(const uint4*)(Al + (size_t)(m0 + 32 + lrow) * NDIN + k0);
    al3.q = *(const uint4*)(Al + (size_t)(m0 + 48 + lrow) * NDIN + k0);
    acc0 = __builtin_amdgcn_mfma_f32_16x16x32_bf16(ah0.v, bh.v, acc0, 0, 0, 0);
    acc0 = __builtin_amdgcn_mfma_f32_16x16x32_bf16(ah0.v, bl.v, acc0, 0, 0, 0);
    acc0 = __builtin_amdgcn_mfma_f32_16x16x32_bf16(al0.v, bh.v, acc0, 0, 0, 0);
    acc1 = __builtin_amdgcn_mfma_f32_16x16x32_bf16(ah1.v, bh.v, acc1, 0, 0, 0);
    acc1 = __builtin_amdgcn_mfma_f32_16x16x32_bf16(ah1.v, bl.v, acc1, 0, 0, 0);
    acc1 = __builtin_amdgcn_mfma_f32_16x16x32_bf16(al1.v, bh.v, acc1, 0, 0, 0);
    acc2 = __builtin_amdgcn_mfma_f32_16x16x32_bf16(ah2.v, bh.v, acc2, 0, 0, 0);
    acc2 = __builtin_amdgcn_mfma_f32_16x16x32_bf16(ah2.v, bl.v, acc2, 0, 0, 0);
    acc2 = __builtin_amdgcn_mfma_f32_16x16x32_bf16(al2.v, bh.v, acc2, 0, 0, 0);
    acc3 = __builtin_amdgcn_mfma_f32_16x16x32_bf16(ah3.v, bh.v, acc3, 0, 0, 0);
    acc3 = __builtin_amdgcn_mfma_f32_16x16x32_bf16(ah3.v, bl.v, acc3, 0, 0, 0);
    acc3 = __builtin_amdgcn_mfma_f32_16x16x32_bf16(al3.v, bh.v, acc3, 0, 0, 0);
  }
  int col = nt * 16 + lrow;
  float bias = dir ? (bih_b[col] + bhh_b[col]) : (bih_f[col] + bhh_f[col]);
  float* gb = gbase + (size_t)dir * NSB * NG;
  int rb = (lane >> 4) * 4;
  #pragma unroll
  for (int rr = 0; rr < 4; rr++) {
    gb[(size_t)(m0 +  0 + rb + rr) * NG + col] = acc0[rr] + bias;
    gb[(size_t)(m0 + 16 + rb + rr) * NG + col] = acc1[rr] + bias;
    gb[(size_t)(m0 + 32 + rb + rr) * NG + col] = acc2[rr] + bias;
    gb[(size_t)(m0 + 48 + rb + rr) * NG + col] = acc3[rr] + bias;
  }
}

// ---------------- persistent bidirectional LSTM: 16 blocks ------------------
// R8-proven verbatim: tagged 16B granules {tag, hi2, lo2, pad}; thread tid
// owns granules s = tid + q*512 (CONSECUTIVE 16B per lane per instruction =
// fully coalesced poll); single asm block holds loads + vmcnt(0) so no
// un-retired asm outputs are visible to the compiler.
__global__ __launch_bounds__(512, 2) void k_lstm(
    const float* __restrict__ whh_f_, const float* __restrict__ whh_b_,
    const float* __restrict__ gbase, const int* __restrict__ slen,
    uint32_t* __restrict__ gr)
{
  int wg = blockIdx.x;
  int dir = wg >> 3, p = wg & 7;
  int u0 = p * 32;
  int tid = threadIdx.x, wave = tid >> 6, lane = tid & 63;
  int lrow = lane & 15, lkb = (lane >> 4) * 8;
  const float* Wr = dir ? whh_b_ : whh_f_;
  const float* gb = gbase + (size_t)dir * NSB * NG;
  uint32_t* grd = gr + (size_t)dir * 2 * NB * 128 * 4;  // [par][batch][unitpair]{4xu32}

  __shared__ __attribute__((aligned(16))) uint16_t hs[2][NB][264];
  __shared__ float tscr[8][32 * 18];

  // W frags hi+lo: wave tile col c -> weight row (c>>2)*256 + u0 + wave*4 + (c&3)
  bfrag wh[8], wl[8];
  {
    int wr = (lrow >> 2) * 256 + u0 + wave * 4 + (lrow & 3);
    const float* wrow = Wr + (size_t)wr * NH;
    #pragma unroll
    for (int kk = 0; kk < 8; kk++) {
      int k0 = kk * 32 + lkb;
      bfrag th, tl;
      #pragma unroll
      for (int e = 0; e < 8; e++) {
        float v0 = wrow[k0 + e];
        uint16_t h0_ = f2bf(v0);
        th.u[e] = h0_; tl.u[e] = f2bf(v0 - bf2f(h0_));
      }
      wh[kk] = th; wl[kk] = tl;
    }
  }
  int beta = lane >> 1;                     // batch owned in pointwise
  int upg = p * 16 + wave * 2 + (lane & 1); // global unitpair owned (2 units)
  int len = slen[beta];
  uint32_t hprev_hi = 0, hprev_lo = 0;
  float c0 = 0.0f, c1 = 0.0f;

  unsigned long long sa[2][8];
  #pragma unroll
  for (int par = 0; par < 2; par++) {
    const uint32_t* gpar = grd + (size_t)par * NB * 128 * 4;
    #pragma unroll
    for (int q = 0; q < 8; q++)
      sa[par][q] = (unsigned long long)(uintptr_t)(gpar + (size_t)(tid + q * 512) * 4);
  }

  for (int i = 0; i < NS; i++) {
    int t = dir ? (NS - 1 - i) : i;
    // ---- g prefetch (plain loads, overlap the granule wait) ----
    const float* gptr = gb + ((size_t)t * NB + beta) * NG + u0 + wave * 4 + (lane & 1) * 2;
    f2arr g0, g1, g2, g3;
    g0.v = *(const float2*)(gptr);
    g1.v = *(const float2*)(gptr + 256);
    g2.v = *(const float2*)(gptr + 512);
    g3.v = *(const float2*)(gptr + 768);
    // ---- tagged-granule fetch: 8 x 16B sc1, retry until tags >= i ----
    u32x4 v0, v1, v2, v3, v4, v5, v6, v7;
    {
      const unsigned long long* a = sa[i & 1];
      uint32_t need = (uint32_t)i;
      long spins = 0;
      for (;;) {
        asm volatile(
          "global_load_dwordx4 %0, %8, off sc1\n\t"
          "global_load_dwordx4 %1, %9, off sc1\n\t"
          "global_load_dwordx4 %2, %10, off sc1\n\t"
          "global_load_dwordx4 %3, %11, off sc1\n\t"
          "global_load_dwordx4 %4, %12, off sc1\n\t"
          "global_load_dwordx4 %5, %13, off sc1\n\t"
          "global_load_dwordx4 %6, %14, off sc1\n\t"
          "global_load_dwordx4 %7, %15, off sc1\n\t"
          "s_waitcnt vmcnt(0)"
          : "=&v"(v0), "=&v"(v1), "=&v"(v2), "=&v"(v3),
            "=&v"(v4), "=&v"(v5), "=&v"(v6), "=&v"(v7)
          : "v"(a[0]), "v"(a[1]), "v"(a[2]), "v"(a[3]),
            "v"(a[4]), "v"(a[5]), "v"(a[6]), "v"(a[7])
          : "memory");
        if (v0.x >= need && v1.x >= need && v2.x >= need && v3.x >= need &&
            v4.x >= need && v5.x >= need && v6.x >= need && v7.x >= need) break;
        if (++spins > (1L << 16)) break;   // safety: wrong-answer, not hang
      }
    }
    __syncthreads();                       // prev-step hs fully consumed
    // ---- scatter granules into hs (hi plane 0, lo plane 1) ----
    #pragma unroll
    for (int q = 0; q < 8; q++) {
      int idx = tid + q * 512;
      int bb = idx >> 7, up = idx & 127;
      u32x4 vv = (q == 0) ? v0 : (q == 1) ? v1 : (q == 2) ? v2 : (q == 3) ? v3
               : (q == 4) ? v4 : (q == 5) ? v5 : (q == 6) ? v6 : v7;
      *(uint32_t*)(&hs[0][bb][up * 2]) = vv.y;
      *(uint32_t*)(&hs[1][bb][up * 2]) = vv.z;
    }
    __syncthreads();                       // hs ready
    // ---- recurrent MFMA: acc = Ah*Wh + Ah*Wl + Al*Wh ----
    f32x4 acc0 = {0,0,0,0}, acc1 = acc0;
    #pragma unroll
    for (int kk = 0; kk < 8; kk++) {
      int k0 = kk * 32 + lkb;
      bfrag ah0, ah1, al0, al1;
      ah0.q = *(const uint4*)(&hs[0][lrow][k0]);
      ah1.q = *(const uint4*)(&hs[0][16 + lrow][k0]);
      al0.q = *(const uint4*)(&hs[1][lrow][k0]);
      al1.q = *(const uint4*)(&hs[1][16 + lrow][k0]);
      acc0 = __builtin_amdgcn_mfma_f32_16x16x32_bf16(ah0.v, wh[kk].v, acc0, 0, 0, 0);
      acc0 = __builtin_amdgcn_mfma_f32_16x16x32_bf16(ah0.v, wl[kk].v, acc0, 0, 0, 0);
      acc0 = __builtin_amdgcn_mfma_f32_16x16x32_bf16(al0.v, wh[kk].v, acc0, 0, 0, 0);
      acc1 = __builtin_amdgcn_mfma_f32_16x16x32_bf16(ah1.v, wh[kk].v, acc1, 0, 0, 0);
      acc1 = __builtin_amdgcn_mfma_f32_16x16x32_bf16(ah1.v, wl[kk].v, acc1, 0, 0, 0);
      acc1 = __builtin_amdgcn_mfma_f32_16x16x32_bf16(al1.v, wh[kk].v, acc1, 0, 0, 0);
    }
    // ---- intra-wave transpose (volatile LDS, same-wave ordering) ----
    volatile float* ts = &tscr[wave][0];
    {
      int colT = lane & 15, rb = (lane >> 4) * 4;
      #pragma unroll
      for (int rr = 0; rr < 4; rr++) {
        ts[(rb + rr) * 18 + colT]      = acc0[rr];
        ts[(16 + rb + rr) * 18 + colT] = acc1[rr];
      }
    }
    int e2 = (lane & 1) * 2;
    float gv00 = ts[beta * 18 + 0 + e2],  gv01 = ts[beta * 18 + 1 + e2];
    float gv10 = ts[beta * 18 + 4 + e2],  gv11 = ts[beta * 18 + 5 + e2];
    float gv20 = ts[beta * 18 + 8 + e2],  gv21 = ts[beta * 18 + 9 + e2];
    float gv30 = ts[beta * 18 + 12 + e2], gv31 = ts[beta * 18 + 13 + e2];
    // ---- pointwise (fast math) + tagged publish ----
    {
      int upd = (t < len) ? 1 : 0;
      float gi0 = gv00 + g0.a[0], gi1 = gv01 + g0.a[1];
      float gf0 = gv10 + g1.a[0], gf1 = gv11 + g1.a[1];
      float gg0 = gv20 + g2.a[0], gg1 = gv21 + g2.a[1];
      float go0 = gv30 + g3.a[0], go1 = gv31 + g3.a[1];
      float c2a = sig_fast(gf0) * c0 + sig_fast(gi0) * tanh_fast(gg0);
      float c2b = sig_fast(gf1) * c1 + sig_fast(gi1) * tanh_fast(gg1);
      float h2a = sig_fast(go0) * tanh_fast(c2a);
      float h2b = sig_fast(go1) * tanh_fast(c2b);
      c0 = upd ? c2a : c0;
      c1 = upd ? c2b : c1;
      uint32_t hiw, low;
      if (upd) {
        uint16_t ha = f2bf(h2a), hbb = f2bf(h2b);
        uint16_t la = f2bf(h2a - bf2f(ha)), lb = f2bf(h2b - bf2f(hbb));
        hiw = (uint32_t)ha | ((uint32_t)hbb << 16);
        low = (uint32_t)la | ((uint32_t)lb << 16);
      } else { hiw = hprev_hi; low = hprev_lo; }
      hprev_hi = hiw; hprev_lo = low;
      uint32_t* gout = grd + ((size_t)(((i + 1) & 1) * NB + beta) * 128 + upg) * 4;
      u32x4 pv;
      pv.x = (uint32_t)(i + 1); pv.y = hiw; pv.z = low; pv.w = 0u;
      asm volatile("global_store_dwordx4 %0, %1, off sc1"
                   :: "v"((unsigned long long)(uintptr_t)gout), "v"(pv) : "memory");
    }
  }
}

// ---------------- FC + BatchNorm + ReLU + log_softmax(axis=0) ---------------
__global__ __launch_bounds__(1024) void k_final(
    const uint32_t* __restrict__ gr, const float* __restrict__ fc_w,
    const float* __restrict__ fc_b, const float* __restrict__ gamma_,
    const float* __restrict__ beta_, float* __restrict__ outp)
{
  __shared__ float hid[NB][512];
  __shared__ float ylds[NB][NOUT];
  int tid = threadIdx.x;
  // final h: parity 0 (NS=40 even), granule {tag, hi2, lo2, pad}
  for (int idx = tid; idx < NB * 512; idx += 1024) {
    int bb = idx >> 9, k = idx & 511;
    int bsrc = 2 * (bb & 15) + (k >> 8);
    int hcol = k & 255;
    int dirn = (bb < 16) ? 0 : 1;
    const uint32_t* g = gr + ((size_t)dirn * 2 * NB * 128 + (size_t)bsrc * 128 + (hcol >> 1)) * 4;
    uint32_t hi2 = ld_agent_u32(g + 1);
    uint32_t lo2 = ld_agent_u32(g + 2);
    int sh = (hcol & 1) * 16;
    hid[bb][k] = bf2f((uint16_t)(hi2 >> sh)) + bf2f((uint16_t)(lo2 >> sh));
  }
  __syncthreads();
  int o = tid & 127, b0 = tid >> 7;
  float a0 = 0, a1 = 0, a2 = 0, a3 = 0;
  const float4* wrow = (const float4*)(fc_w + (size_t)o * 512);
  for (int k4 = 0; k4 < 128; k4++) {
    float4 w = wrow[k4];
    float4 h0 = *(const float4*)(&hid[b0][k4 * 4]);
    float4 h1 = *(const float4*)(&hid[b0 + 8][k4 * 4]);
    float4 h2 = *(const float4*)(&hid[b0 + 16][k4 * 4]);
    float4 h3 = *(const float4*)(&hid[b0 + 24][k4 * 4]);
    a0 += w.x * h0.x + w.y * h0.y + w.z * h0.z + w.w * h0.w;
    a1 += w.x * h1.x + w.y * h1.y + w.z * h1.z + w.w * h1.w;
    a2 += w.x * h2.x + w.y * h2.y + w.z * h2.z + w.w * h2.w;
    a3 += w.x * h3.x + w.y * h3.y + w.z * h3.z + w.w * h3.w;
  }
  float bias = fc_b[o];
  ylds[b0][o]      = a0 + bias;
  ylds[b0 + 8][o]  = a1 + bias;
  ylds[b0 + 16][o] = a2 + bias;
  ylds[b0 + 24][o] = a3 + bias;
  __syncthreads();
  if (tid < NOUT) {
    float mu = 0;
    for (int bb = 0; bb < NB; bb++) mu += ylds[bb][tid];
    mu *= (1.0f / NB);
    float var = 0;
    for (int bb = 0; bb < NB; bb++) { float d = ylds[bb][tid] - mu; var += d * d; }
    var *= (1.0f / NB);
    float g = gamma_[tid], be = beta_[tid];
    float inv = 1.0f / sqrtf(var + 1e-5f);
    float ym = -1e30f;
    for (int bb = 0; bb < NB; bb++) {
      float y = g * (ylds[bb][tid] - mu) * inv + be;
      y = fmaxf(y, 0.0f);
      ylds[bb][tid] = y;
      if (y > ym) ym = y;
    }
    float se = 0;
    for (int bb = 0; bb < NB; bb++) se += expf(ylds[bb][tid] - ym);
    float lse = ym + logf(se);
    for (int bb = 0; bb < NB; bb++) outp[bb * NOUT + tid] = ylds[bb][tid] - lse;
  }
}

extern "C" void kernel_launch(void* const* d_in, const int* in_sizes, int n_in,
                              void* d_out, int out_size, void* d_ws, size_t ws_size,
                              hipStream_t stream) {
  (void)in_sizes; (void)n_in; (void)out_size; (void)ws_size;
  const int*   x      = (const int*)  d_in[0];
  const void*  xmask  =               d_in[1];
  const float* xfeat  = (const float*)d_in[2];
  const int*   slen   = (const int*)  d_in[3];
  const float* emb    = (const float*)d_in[6];
  const float* attn_w = (const float*)d_in[7];
  const float* wih_f  = (const float*)d_in[9];
  const float* whh_f  = (const float*)d_in[10];
  const float* bih_f  = (const float*)d_in[11];
  const float* bhh_f  = (const float*)d_in[12];
  const float* wih_b  = (const float*)d_in[13];
  const float* whh_b  = (const float*)d_in[14];
  const float* bih_b  = (const float*)d_in[15];
  const float* bhh_b  = (const float*)d_in[16];
  const float* fc_w   = (const float*)d_in[17];
  const float* fc_b   = (const float*)d_in[18];
  const float* gam    = (const float*)d_in[19];
  const float* bet    = (const float*)d_in[20];

  char* ws = (char*)d_ws;
  int*      flag  = (int*)ws;                        // [0, 4096): mask-dtype flag
  uint32_t* gr    = (uint32_t*)(ws + 4096);          // granules 2dir x 2par x 32x128 x 16B (262,144 B)
  uint16_t* Xb    = (uint16_t*)(ws + 266240);        // 2 planes x 1280x320 bf16 (1,638,400 B)
  uint16_t* wihb  = (uint16_t*)(ws + 1904640);       // 4 planes x 1024x320 bf16 (2,621,440 B)
  float*    gbase = (float*)(ws + 4526080);          // 2x1280x1024 f32 (10,485,760 B)

  hipMemsetAsync(ws, 0, 266240, stream);             // flag + granule tags/data in one shot
  k_detect<<<1, 256, 0, stream>>>((const uint32_t*)xmask, flag);
  k_attn_prep<<<2560, 256, 0, stream>>>(x, xmask, xfeat, slen, emb, attn_w, Xb, flag,
                                        wih_f, wih_b, wihb);
  k_gbase<<<320, 512, 0, stream>>>(Xb, wihb, bih_f, bhh_f, bih_b, bhh_b, gbase);
  k_lstm<<<16, 512, 0, stream>>>(whh_f, whh_b, gbase, slen, gr);
  k_final<<<1, 1024, 0, stream>>>(gr, fc_w, fc_b, gam, bet, (float*)d_out);
}

// Round 12
// 307.960 us; speedup vs baseline: 1.8924x; 1.2371x over previous
//
#include <hip/hip_runtime.h>
#include <stdint.h>

#define NB 32
#define NS 40
#define NT 60
#define NH 256
#define NF 64
#define NDIN 320
#define NG 1024
#define NSB 1280
#define NOUT 128

typedef __bf16 bf16x8 __attribute__((ext_vector_type(8)));
typedef float f32x4 __attribute__((ext_vector_type(4)));
typedef uint32_t u32x4 __attribute__((ext_vector_type(4)));

union bfrag { bf16x8 v; uint16_t u[8]; uint4 q; uint64_t d[2]; };
union f2arr { float2 v; float a[2]; };

__device__ __forceinline__ uint16_t f2bf(float f) {
  uint32_t u = __float_as_uint(f);
  u += 0x7fffu + ((u >> 16) & 1u);
  return (uint16_t)(u >> 16);
}
__device__ __forceinline__ float bf2f(uint16_t h) {
  return __uint_as_float(((uint32_t)h) << 16);
}
__device__ __forceinline__ float sig_fast(float x) { return 1.0f / (1.0f + __expf(-x)); }
__device__ __forceinline__ float tanh_fast(float x) {
  x = fminf(fmaxf(x, -15.0f), 15.0f);
  float t = __expf(2.0f * x);
  return (t - 1.0f) / (t + 1.0f);
}
__device__ __forceinline__ uint32_t ld_agent_u32(const uint32_t* p) {
  return __hip_atomic_load(p, __ATOMIC_RELAXED, __HIP_MEMORY_SCOPE_AGENT);
}

// ---------------- mask dtype detector: 0=int32, 1=bytes(bool), 2=float32 ----
__global__ void k_detect(const uint32_t* __restrict__ xm, int* __restrict__ flag) {
  __shared__ int s_notint, s_notflt;
  if (threadIdx.x == 0) { s_notint = 0; s_notflt = 0; }
  __syncthreads();
  int notint = 0, notflt = 0;
  for (int i = threadIdx.x; i < 19200; i += 256) {   // 76800B: safe all dtypes
    uint32_t v = xm[i];
    if (v > 1u) notint = 1;
    if (v != 0u && v != 0x3f800000u) notflt = 1;
  }
  if (notint) atomicOr(&s_notint, 1);
  if (notflt) atomicOr(&s_notflt, 1);
  __syncthreads();
  if (threadIdx.x == 0) {
    int f;
    if (!s_notint) f = 0;
    else if (!s_notflt) f = 2;
    else f = 1;
    *flag = f;
  }
}

// ------- merged: blocks [0,1280) attention pooling; [1280,2560) wih prep ----
__global__ __launch_bounds__(256) void k_attn_prep(
    const int* __restrict__ x, const void* __restrict__ xmask,
    const float* __restrict__ xfeat, const int* __restrict__ slen,
    const float* __restrict__ emb, const float* __restrict__ attn_w,
    uint16_t* __restrict__ Xb, const int* __restrict__ flagp,
    const float* __restrict__ wf, const float* __restrict__ wb,
    uint16_t* __restrict__ outw)
{
  int tid = threadIdx.x;
  if (blockIdx.x >= 1280) {              // ---- wih -> hi/lo bf16 planes ----
    const int n = NG * NDIN;
    for (int idx = (blockIdx.x - 1280) * 256 + tid; idx < 2 * n; idx += 1280 * 256) {
      float v = (idx < n) ? wf[idx] : wb[idx - n];
      uint16_t hi = f2bf(v);
      outw[idx] = hi;
      outw[2 * n + idx] = f2bf(v - bf2f(hi));
    }
    return;
  }
  int bs = blockIdx.x;
  int b = bs / NS, s = bs % NS;
  uint16_t* Xh = Xb + (size_t)(s * NB + b) * NDIN;
  uint16_t* Xl = Xh + (size_t)NSB * NDIN;
  int len = slen[b];
  if (s >= len) {
    for (int i = tid; i < NDIN; i += 256) { Xh[i] = 0; Xl[i] = 0; }
    return;
  }
  __shared__ __attribute__((aligned(16))) float sw[NH];
  __shared__ float salpha[NT];
  __shared__ int sidx[NT];
  __shared__ unsigned char svalid[NT];
  __shared__ __attribute__((aligned(16))) uint16_t es[NT][NH];
  sw[tid] = attn_w[tid];
  int flag = *flagp;
  if (tid < NT) {
    int mi = bs * NT + tid;
    sidx[tid] = x[mi];
    int mv;
    if (flag == 1)      mv = ((const unsigned char*)xmask)[mi];
    else if (flag == 2) mv = (((const float*)xmask)[mi] != 0.0f) ? 1 : 0;
    else                mv = ((const int*)xmask)[mi];
    svalid[tid] = (mv == 0) ? 1 : 0;
  }
  __syncthreads();
  int wave = tid >> 6, lane = tid & 63;
  for (int t = wave; t < NT; t += 4) {
    float d = 0.0f;
    if (svalid[t]) {
      const float* er = emb + (size_t)sidx[t] * NH;
      float4 e4 = ((const float4*)er)[lane];
      float4 w4 = ((const float4*)sw)[lane];
      uint16_t* ed = &es[t][lane * 4];
      ed[0] = f2bf(e4.x); ed[1] = f2bf(e4.y); ed[2] = f2bf(e4.z); ed[3] = f2bf(e4.w);
      d = e4.x * w4.x + e4.y * w4.y + e4.z * w4.z + e4.w * w4.w;
      #pragma unroll
      for (int o = 32; o > 0; o >>= 1) d += __shfl_down(d, o);
    }
    if (lane == 0) salpha[t] = d;
  }
  __syncthreads();
  if (tid < 64) {                        // wave-parallel softmax over <=60 tokens
    int valid = (tid < NT) && svalid[tid];
    float v = valid ? salpha[tid] : -1e30f;
    float m = v;
    #pragma unroll
    for (int o = 32; o > 0; o >>= 1) m = fmaxf(m, __shfl_xor(m, o));
    float e = valid ? expf(v - m) : 0.0f;
    float ssum = e;
    #pragma unroll
    for (int o = 32; o > 0; o >>= 1) ssum += __shfl_xor(ssum, o);
    if (tid < NT) salpha[tid] = e / ssum;
  }
  __syncthreads();
  float acc = 0.0f;
  for (int t = 0; t < NT; t++) {
    float a = salpha[t];
    if (a != 0.0f) acc += a * bf2f(es[t][tid]);
  }
  {
    uint16_t hi = f2bf(acc);
    Xh[tid] = hi; Xl[tid] = f2bf(acc - bf2f(hi));
  }
  if (tid < NF) {
    float fa = 0.0f;
    const float* fp = xfeat + (size_t)bs * NT * NF + tid;
    for (int t = 0; t < NT; t++) if (svalid[t]) fa += fp[t * NF];
    uint16_t hi = f2bf(fa);
    Xh[NH + tid] = hi; Xl[NH + tid] = f2bf(fa - bf2f(hi));
  }
}

// ------- gbase = X @ wih^T + bih + bhh, hi/lo split operands ----------------
__global__ __launch_bounds__(512) void k_gbase(
    const uint16_t* __restrict__ Xb, const uint16_t* __restrict__ wihb,
    const float* __restrict__ bih_f, const float* __restrict__ bhh_f,
    const float* __restrict__ bih_b, const float* __restrict__ bhh_b,
    float* __restrict__ gbase)
{
  const int n = NG * NDIN;
  int wave = threadIdx.x >> 6, lane = threadIdx.x & 63;
  int job = blockIdx.x * 8 + wave;
  int dir = job / 1280;
  int r = job % 1280;
  int nt = r % 64, ms = r / 64;
  int m0 = ms * 64;
  const uint16_t* Wh = wihb + (size_t)dir * n;
  const uint16_t* Wl = Wh + (size_t)2 * n;
  const uint16_t* Ah = Xb;
  const uint16_t* Al = Xb + (size_t)NSB * NDIN;
  int lrow = lane & 15, lk = (lane >> 4) * 8;
  f32x4 acc0 = {0,0,0,0}, acc1 = acc0, acc2 = acc0, acc3 = acc0;
  for (int kk = 0; kk < 10; kk++) {
    int k0 = kk * 32 + lk;
    bfrag bh, bl, ah0, ah1, ah2, ah3, al0, al1, al2, al3;
    bh.q = *(const uint4*)(Wh + (size_t)(nt * 16 + lrow) * NDIN + k0);
    bl.q = *(const uint4*)(Wl + (size_t)(nt * 16 + lrow) * NDIN + k0);
    ah0.q = *(const uint4*)(Ah + (size_t)(m0 +  0 + lrow) * NDIN + k0);
    ah1.q = *(const uint4*)(Ah + (size_t)(m0 + 16 + lrow) * NDIN + k0);
    ah2.q = *(const uint4*)(Ah + (size_t)(m0 + 32 + lrow) * NDIN + k0);
    ah3.q = *(const uint4*)(Ah + (size_t)(m0 + 48 + lrow) * NDIN + k0);
    al0.q = *(const uint4*)(Al + (size_t)(m0 +  0 + lrow) * NDIN + k0);
    al1.q = *(const uint4*)(Al + (size_t)(m0 + 16 + lrow) * NDIN + k0);
    al2.q = *(const uint4*)(Al + (size_t)(m0 + 32 + lrow) * NDIN + k0);
    al3.q = *(const uint4*)(Al + (size_t)(m0 + 48 + lrow) * NDIN + k0);
    acc0 = __builtin_amdgcn_mfma_f32_16x16x32_bf16(ah0.v, bh.v, acc0, 0, 0, 0);
    acc0 = __builtin_amdgcn_mfma_f32_16x16x32_bf16(ah0.v, bl.v, acc0, 0, 0, 0);
    acc0 = __builtin_amdgcn_mfma_f32_16x16x32_bf16(al0.v, bh.v, acc0, 0, 0, 0);
    acc1 = __builtin_amdgcn_mfma_f32_16x16x32_bf16(ah1.v, bh.v, acc1, 0, 0, 0);
    acc1 = __builtin_amdgcn_mfma_f32_16x16x32_bf16(ah1.v, bl.v, acc1, 0, 0, 0);
    acc1 = __builtin_amdgcn_mfma_f32_16x16x32_bf16(al1.v, bh.v, acc1, 0, 0, 0);
    acc2 = __builtin_amdgcn_mfma_f32_16x16x32_bf16(ah2.v, bh.v, acc2, 0, 0, 0);
    acc2 = __builtin_amdgcn_mfma_f32_16x16x32_bf16(ah2.v, bl.v, acc2, 0, 0, 0);
    acc2 = __builtin_amdgcn_mfma_f32_16x16x32_bf16(al2.v, bh.v, acc2, 0, 0, 0);
    acc3 = __builtin_amdgcn_mfma_f32_16x16x32_bf16(ah3.v, bh.v, acc3, 0, 0, 0);
    acc3 = __builtin_amdgcn_mfma_f32_16x16x32_bf16(ah3.v, bl.v, acc3, 0, 0, 0);
    acc3 = __builtin_amdgcn_mfma_f32_16x16x32_bf16(al3.v, bh.v, acc3, 0, 0, 0);
  }
  int col = nt * 16 + lrow;
  float bias = dir ? (bih_b[col] + bhh_b[col]) : (bih_f[col] + bhh_f[col]);
  float* gb = gbase + (size_t)dir * NSB * NG;
  int rb = (lane >> 4) * 4;
  #pragma unroll
  for (int rr = 0; rr < 4; rr++) {
    gb[(size_t)(m0 +  0 + rb + rr) * NG + col] = acc0[rr] + bias;
    gb[(size_t)(m0 + 16 + rb + rr) * NG + col] = acc1[rr] + bias;
    gb[(size_t)(m0 + 32 + rb + rr) * NG + col] = acc2[rr] + bias;
    gb[(size_t)(m0 + 48 + rb + rr) * NG + col] = acc3[rr] + bias;
  }
}

// ---------------- persistent bidirectional LSTM: 16 blocks ------------------
// Single-plane recurrence (R2-validated precision: h and whh plain bf16; the
// hi/lo split lives only in gbase). Tagged 16B granules now carry 4 units:
// {tag, hi_pair0, hi_pair1, pad}, layout [par][g64][batch] so producer stores
// AND consumer poll loads are fully coalesced. Poll = R8-proven single asm
// block (loads + vmcnt(0) inside, nothing un-retired visible to compiler),
// now 4 loads/thread (32KB/block-step instead of 64KB).
__global__ __launch_bounds__(512, 2) void k_lstm(
    const float* __restrict__ whh_f_, const float* __restrict__ whh_b_,
    const float* __restrict__ gbase, const int* __restrict__ slen,
    uint32_t* __restrict__ gr)
{
  int wg = blockIdx.x;
  int dir = wg >> 3, p = wg & 7;
  int u0 = p * 32;
  int tid = threadIdx.x, wave = tid >> 6, lane = tid & 63;
  int lrow = lane & 15, lkb = (lane >> 4) * 8;
  const float* Wr = dir ? whh_b_ : whh_f_;
  const float* gb = gbase + (size_t)dir * NSB * NG;
  uint32_t* grd = gr + (size_t)dir * 2 * 64 * NB * 4;   // [par][g64][batch]{4xu32}

  __shared__ __attribute__((aligned(16))) uint16_t hs[NB][264];
  __shared__ float tscr[8][32 * 18];

  // W frags (hi only): wave tile col c -> weight row (c>>2)*256 + u0 + wave*4 + (c&3)
  bfrag wh[8];
  {
    int wr = (lrow >> 2) * 256 + u0 + wave * 4 + (lrow & 3);
    const float* wrow = Wr + (size_t)wr * NH;
    #pragma unroll
    for (int kk = 0; kk < 8; kk++) {
      int k0 = kk * 32 + lkb;
      bfrag th;
      #pragma unroll
      for (int e = 0; e < 8; e++) th.u[e] = f2bf(wrow[k0 + e]);
      wh[kk] = th;
    }
  }
  int beta = lane >> 1;                     // batch owned in pointwise
  int g64 = p * 8 + wave;                   // 4-unit granule owned (even lanes publish)
  int len = slen[beta];
  uint32_t hprev_hi = 0;
  float c0 = 0.0f, c1 = 0.0f;

  unsigned long long sa[2][4];
  #pragma unroll
  for (int par = 0; par < 2; par++) {
    const uint32_t* gpar = grd + (size_t)par * 64 * NB * 4;
    #pragma unroll
    for (int q = 0; q < 4; q++)
      sa[par][q] = (unsigned long long)(uintptr_t)(gpar + (size_t)(tid + q * 512) * 4);
  }

  for (int i = 0; i < NS; i++) {
    int t = dir ? (NS - 1 - i) : i;
    // ---- g prefetch (plain loads, overlap the granule wait) ----
    const float* gptr = gb + ((size_t)t * NB + beta) * NG + u0 + wave * 4 + (lane & 1) * 2;
    f2arr g0, g1, g2, g3;
    g0.v = *(const float2*)(gptr);
    g1.v = *(const float2*)(gptr + 256);
    g2.v = *(const float2*)(gptr + 512);
    g3.v = *(const float2*)(gptr + 768);
    // ---- tagged-granule fetch: 4 x 16B sc1, retry until tags >= i ----
    u32x4 v0, v1, v2, v3;
    {
      const unsigned long long* a = sa[i & 1];
      uint32_t need = (uint32_t)i;
      long spins = 0;
      for (;;) {
        asm volatile(
          "global_load_dwordx4 %0, %4, off sc1\n\t"
          "global_load_dwordx4 %1, %5, off sc1\n\t"
          "global_load_dwordx4 %2, %6, off sc1\n\t"
          "global_load_dwordx4 %3, %7, off sc1\n\t"
          "s_waitcnt vmcnt(0)"
          : "=&v"(v0), "=&v"(v1), "=&v"(v2), "=&v"(v3)
          : "v"(a[0]), "v"(a[1]), "v"(a[2]), "v"(a[3])
          : "memory");
        if (v0.x >= need && v1.x >= need && v2.x >= need && v3.x >= need) break;
        if (++spins > (1L << 16)) break;   // safety: wrong-answer, not hang
      }
    }
    __syncthreads();                       // prev-step hs fully consumed
    // ---- scatter granules: s = tid + q*512 -> g64 = s>>5, bb = s&31 ----
    #pragma unroll
    for (int q = 0; q < 4; q++) {
      int s = tid + q * 512;
      int gq = s >> 5, bb = s & 31;
      u32x4 vv = (q == 0) ? v0 : (q == 1) ? v1 : (q == 2) ? v2 : v3;
      uint32_t* d = (uint32_t*)(&hs[bb][gq * 4]);
      d[0] = vv.y; d[1] = vv.z;
    }
    __syncthreads();                       // hs ready
    // ---- recurrent MFMA: acc = Ah * Wh ----
    f32x4 acc0 = {0,0,0,0}, acc1 = acc0;
    #pragma unroll
    for (int kk = 0; kk < 8; kk++) {
      int k0 = kk * 32 + lkb;
      bfrag ah0, ah1;
      ah0.q = *(const uint4*)(&hs[lrow][k0]);
      ah1.q = *(const uint4*)(&hs[16 + lrow][k0]);
      acc0 = __builtin_amdgcn_mfma_f32_16x16x32_bf16(ah0.v, wh[kk].v, acc0, 0, 0, 0);
      acc1 = __builtin_amdgcn_mfma_f32_16x16x32_bf16(ah1.v, wh[kk].v, acc1, 0, 0, 0);
    }
    // ---- intra-wave transpose (volatile LDS, same-wave ordering) ----
    volatile float* ts = &tscr[wave][0];
    {
      int colT = lane & 15, rb = (lane >> 4) * 4;
      #pragma unroll
      for (int rr = 0; rr < 4; rr++) {
        ts[(rb + rr) * 18 + colT]      = acc0[rr];
        ts[(16 + rb + rr) * 18 + colT] = acc1[rr];
      }
    }
    int e2 = (lane & 1) * 2;
    float gv00 = ts[beta * 18 + 0 + e2],  gv01 = ts[beta * 18 + 1 + e2];
    float gv10 = ts[beta * 18 + 4 + e2],  gv11 = ts[beta * 18 + 5 + e2];
    float gv20 = ts[beta * 18 + 8 + e2],  gv21 = ts[beta * 18 + 9 + e2];
    float gv30 = ts[beta * 18 + 12 + e2], gv31 = ts[beta * 18 + 13 + e2];
    // ---- pointwise (fast math) + packed publish (even lanes) ----
    {
      int upd = (t < len) ? 1 : 0;
      float gi0 = gv00 + g0.a[0], gi1 = gv01 + g0.a[1];
      float gf0 = gv10 + g1.a[0], gf1 = gv11 + g1.a[1];
      float gg0 = gv20 + g2.a[0], gg1 = gv21 + g2.a[1];
      float go0 = gv30 + g3.a[0], go1 = gv31 + g3.a[1];
      float c2a = sig_fast(gf0) * c0 + sig_fast(gi0) * tanh_fast(gg0);
      float c2b = sig_fast(gf1) * c1 + sig_fast(gi1) * tanh_fast(gg1);
      float h2a = sig_fast(go0) * tanh_fast(c2a);
      float h2b = sig_fast(go1) * tanh_fast(c2b);
      c0 = upd ? c2a : c0;
      c1 = upd ? c2b : c1;
      uint32_t hiw;
      if (upd) {
        uint16_t ha = f2bf(h2a), hbb = f2bf(h2b);
        hiw = (uint32_t)ha | ((uint32_t)hbb << 16);
      } else hiw = hprev_hi;
      hprev_hi = hiw;
      uint32_t hiw_p = __shfl_down(hiw, 1);   // partner (odd lane) pair
      if ((lane & 1) == 0) {
        uint32_t* gout = grd + ((size_t)(((i + 1) & 1) * 64 + g64) * NB + beta) * 4;
        u32x4 pv;
        pv.x = (uint32_t)(i + 1); pv.y = hiw; pv.z = hiw_p; pv.w = 0u;
        asm volatile("global_store_dwordx4 %0, %1, off sc1"
                     :: "v"((unsigned long long)(uintptr_t)gout), "v"(pv) : "memory");
      }
    }
  }
}

// ---------------- FC + BatchNorm + ReLU + log_softmax(axis=0) ---------------
__global__ __launch_bounds__(1024) void k_final(
    const uint32_t* __restrict__ gr, const float* __restrict__ fc_w,
    const float* __restrict__ fc_b, const float* __restrict__ gamma_,
    const float* __restrict__ beta_, float* __restrict__ outp)
{
  __shared__ float hid[NB][512];
  __shared__ float ylds[NB][NOUT];
  int tid = threadIdx.x;
  // final h: parity 0 (NS=40 even); granule {tag, hi_pair0, hi_pair1, pad},
  // layout [dir][par][g64][batch]; unit hcol -> g64 = hcol>>2, word = 1+((hcol>>1)&1)
  for (int idx = tid; idx < NB * 512; idx += 1024) {
    int bb = idx >> 9, k = idx & 511;
    int bsrc = 2 * (bb & 15) + (k >> 8);
    int hcol = k & 255;
    int dirn = (bb < 16) ? 0 : 1;
    const uint32_t* g = gr + ((size_t)dirn * 2 * 64 * NB + (size_t)(hcol >> 2) * NB + bsrc) * 4;
    uint32_t w = ld_agent_u32(g + 1 + ((hcol >> 1) & 1));
    hid[bb][k] = bf2f((uint16_t)(w >> ((hcol & 1) * 16)));
  }
  __syncthreads();
  int o = tid & 127, b0 = tid >> 7;
  float a0 = 0, a1 = 0, a2 = 0, a3 = 0;
  const float4* wrow = (const float4*)(fc_w + (size_t)o * 512);
  for (int k4 = 0; k4 < 128; k4++) {
    float4 w = wrow[k4];
    float4 h0 = *(const float4*)(&hid[b0][k4 * 4]);
    float4 h1 = *(const float4*)(&hid[b0 + 8][k4 * 4]);
    float4 h2 = *(const float4*)(&hid[b0 + 16][k4 * 4]);
    float4 h3 = *(const float4*)(&hid[b0 + 24][k4 * 4]);
    a0 += w.x * h0.x + w.y * h0.y + w.z * h0.z + w.w * h0.w;
    a1 += w.x * h1.x + w.y * h1.y + w.z * h1.z + w.w * h1.w;
    a2 += w.x * h2.x + w.y * h2.y + w.z * h2.z + w.w * h2.w;
    a3 += w.x * h3.x + w.y * h3.y + w.z * h3.z + w.w * h3.w;
  }
  float bias = fc_b[o];
  ylds[b0][o]      = a0 + bias;
  ylds[b0 + 8][o]  = a1 + bias;
  ylds[b0 + 16][o] = a2 + bias;
  ylds[b0 + 24][o] = a3 + bias;
  __syncthreads();
  if (tid < NOUT) {
    float mu = 0;
    for (int bb = 0; bb < NB; bb++) mu += ylds[bb][tid];
    mu *= (1.0f / NB);
    float var = 0;
    for (int bb = 0; bb < NB; bb++) { float d = ylds[bb][tid] - mu; var += d * d; }
    var *= (1.0f / NB);
    float g = gamma_[tid], be = beta_[tid];
    float inv = 1.0f / sqrtf(var + 1e-5f);
    float ym = -1e30f;
    for (int bb = 0; bb < NB; bb++) {
      float y = g * (ylds[bb][tid] - mu) * inv + be;
      y = fmaxf(y, 0.0f);
      ylds[bb][tid] = y;
      if (y > ym) ym = y;
    }
    float se = 0;
    for (int bb = 0; bb < NB; bb++) se += expf(ylds[bb][tid] - ym);
    float lse = ym + logf(se);
    for (int bb = 0; bb < NB; bb++) outp[bb * NOUT + tid] = ylds[bb][tid] - lse;
  }
}

extern "C" void kernel_launch(void* const* d_in, const int* in_sizes, int n_in,
                              void* d_out, int out_size, void* d_ws, size_t ws_size,
                              hipStream_t stream) {
  (void)in_sizes; (void)n_in; (void)out_size; (void)ws_size;
  const int*   x      = (const int*)  d_in[0];
  const void*  xmask  =               d_in[1];
  const float* xfeat  = (const float*)d_in[2];
  const int*   slen   = (const int*)  d_in[3];
  const float* emb    = (const float*)d_in[6];
  const float* attn_w = (const float*)d_in[7];
  const float* wih_f  = (const float*)d_in[9];
  const float* whh_f  = (const float*)d_in[10];
  const float* bih_f  = (const float*)d_in[11];
  const float* bhh_f  = (const float*)d_in[12];
  const float* wih_b  = (const float*)d_in[13];
  const float* whh_b  = (const float*)d_in[14];
  const float* bih_b  = (const float*)d_in[15];
  const float* bhh_b  = (const float*)d_in[16];
  const float* fc_w   = (const float*)d_in[17];
  const float* fc_b   = (const float*)d_in[18];
  const float* gam    = (const float*)d_in[19];
  const float* bet    = (const float*)d_in[20];

  char* ws = (char*)d_ws;
  int*      flag  = (int*)ws;                        // [0, 4096): mask-dtype flag
  uint32_t* gr    = (uint32_t*)(ws + 4096);          // granules 2dir x 2par x 64 x 32 x 16B (131,072 B)
  uint16_t* Xb    = (uint16_t*)(ws + 135168);        // 2 planes x 1280x320 bf16 (1,638,400 B)
  uint16_t* wihb  = (uint16_t*)(ws + 1773568);       // 4 planes x 1024x320 bf16 (2,621,440 B)
  float*    gbase = (float*)(ws + 4395008);          // 2x1280x1024 f32 (10,485,760 B)

  hipMemsetAsync(ws, 0, 135168, stream);             // flag + granule tags/data in one shot
  k_detect<<<1, 256, 0, stream>>>((const uint32_t*)xmask, flag);
  k_attn_prep<<<2560, 256, 0, stream>>>(x, xmask, xfeat, slen, emb, attn_w, Xb, flag,
                                        wih_f, wih_b, wihb);
  k_gbase<<<320, 512, 0, stream>>>(Xb, wihb, bih_f, bhh_f, bih_b, bhh_b, gbase);
  k_lstm<<<16, 512, 0, stream>>>(whh_f, whh_b, gbase, slen, gr);
  k_final<<<1, 1024, 0, stream>>>(gr, fc_w, fc_b, gam, bet, (float*)d_out);
}

// Round 13
// 241.480 us; speedup vs baseline: 2.4133x; 1.2753x over previous
//
#include <hip/hip_runtime.h>
#include <stdint.h>

#define NB 32
#define NS 40
#define NT 60
#define NH 256
#define NF 64
#define NDIN 320
#define NG 1024
#define NSB 1280
#define NOUT 128

typedef __bf16 bf16x8 __attribute__((ext_vector_type(8)));
typedef float f32x4 __attribute__((ext_vector_type(4)));
typedef uint32_t u32x4 __attribute__((ext_vector_type(4)));

union bfrag { bf16x8 v; uint16_t u[8]; uint4 q; uint64_t d[2]; };
union f2arr { float2 v; float a[2]; };

__device__ __forceinline__ uint16_t f2bf(float f) {
  uint32_t u = __float_as_uint(f);
  u += 0x7fffu + ((u >> 16) & 1u);
  return (uint16_t)(u >> 16);
}
__device__ __forceinline__ float bf2f(uint16_t h) {
  return __uint_as_float(((uint32_t)h) << 16);
}
__device__ __forceinline__ float sig_fast(float x) { return 1.0f / (1.0f + __expf(-x)); }
__device__ __forceinline__ float tanh_fast(float x) {
  x = fminf(fmaxf(x, -15.0f), 15.0f);
  float t = __expf(2.0f * x);
  return (t - 1.0f) / (t + 1.0f);
}
__device__ __forceinline__ uint32_t ld_agent_u32(const uint32_t* p) {
  return __hip_atomic_load(p, __ATOMIC_RELAXED, __HIP_MEMORY_SCOPE_AGENT);
}

// ------- detect (32 blocks): classify mask dtype into per-block slots AND
// zero the granule region (replaces hipMemsetAsync). Slot q at flags[8+q]:
// bit0 = not-int32-like, bit1 = not-float-like.
__global__ __launch_bounds__(256) void k_detect(const uint32_t* __restrict__ xm,
                                                int* __restrict__ flags,
                                                uint32_t* __restrict__ gr) {
  int bid = blockIdx.x, tid = threadIdx.x;
  // zero granules: 131072 B = 8192 x 16B; one 16B sc1 store per thread
  {
    int gidx = bid * 256 + tid;
    u32x4 z = {0, 0, 0, 0};
    asm volatile("global_store_dwordx4 %0, %1, off sc1"
                 :: "v"((unsigned long long)(uintptr_t)(gr + (size_t)gidx * 4)), "v"(z)
                 : "memory");
  }
  __shared__ int s_notint, s_notflt;
  if (tid == 0) { s_notint = 0; s_notflt = 0; }
  __syncthreads();
  int notint = 0, notflt = 0;
  for (int i = bid * 600 + tid; i < (bid + 1) * 600; i += 256) {  // 32*600 = 19200 u32
    uint32_t v = xm[i];
    if (v > 1u) notint = 1;
    if (v != 0u && v != 0x3f800000u) notflt = 1;
  }
  if (notint) atomicOr(&s_notint, 1);
  if (notflt) atomicOr(&s_notflt, 1);
  __syncthreads();
  if (tid == 0) flags[8 + bid] = s_notint | (s_notflt << 1);
}

// ------- merged: blocks [0,1280) attention pooling; [1280,2560) wih prep ----
__global__ __launch_bounds__(256) void k_attn_prep(
    const int* __restrict__ x, const void* __restrict__ xmask,
    const float* __restrict__ xfeat, const int* __restrict__ slen,
    const float* __restrict__ emb, const float* __restrict__ attn_w,
    uint16_t* __restrict__ Xb, const int* __restrict__ flagp,
    const float* __restrict__ wf, const float* __restrict__ wb,
    uint16_t* __restrict__ outw)
{
  int tid = threadIdx.x;
  if (blockIdx.x >= 1280) {              // ---- wih -> hi/lo bf16 planes ----
    const int n = NG * NDIN;
    for (int idx = (blockIdx.x - 1280) * 256 + tid; idx < 2 * n; idx += 1280 * 256) {
      float v = (idx < n) ? wf[idx] : wb[idx - n];
      uint16_t hi = f2bf(v);
      outw[idx] = hi;
      outw[2 * n + idx] = f2bf(v - bf2f(hi));
    }
    return;
  }
  int bs = blockIdx.x;
  int b = bs / NS, s = bs % NS;
  uint16_t* Xh = Xb + (size_t)(s * NB + b) * NDIN;
  uint16_t* Xl = Xh + (size_t)NSB * NDIN;
  int len = slen[b];
  if (s >= len) {
    for (int i = tid; i < NDIN; i += 256) { Xh[i] = 0; Xl[i] = 0; }
    return;
  }
  __shared__ __attribute__((aligned(16))) float sw[NH];
  __shared__ float salpha[NT];
  __shared__ int sidx[NT];
  __shared__ unsigned char svalid[NT];
  __shared__ __attribute__((aligned(16))) uint16_t es[NT][NH];
  sw[tid] = attn_w[tid];
  int nv = 0;
  #pragma unroll
  for (int q = 0; q < 32; q++) nv |= flagp[8 + q];
  int flag = (!(nv & 1)) ? 0 : ((!(nv & 2)) ? 2 : 1);
  if (tid < NT) {
    int mi = bs * NT + tid;
    sidx[tid] = x[mi];
    int mv;
    if (flag == 1)      mv = ((const unsigned char*)xmask)[mi];
    else if (flag == 2) mv = (((const float*)xmask)[mi] != 0.0f) ? 1 : 0;
    else                mv = ((const int*)xmask)[mi];
    svalid[tid] = (mv == 0) ? 1 : 0;
  }
  __syncthreads();
  int wave = tid >> 6, lane = tid & 63;
  for (int t = wave; t < NT; t += 4) {
    float d = 0.0f;
    if (svalid[t]) {
      const float* er = emb + (size_t)sidx[t] * NH;
      float4 e4 = ((const float4*)er)[lane];
      float4 w4 = ((const float4*)sw)[lane];
      uint16_t* ed = &es[t][lane * 4];
      ed[0] = f2bf(e4.x); ed[1] = f2bf(e4.y); ed[2] = f2bf(e4.z); ed[3] = f2bf(e4.w);
      d = e4.x * w4.x + e4.y * w4.y + e4.z * w4.z + e4.w * w4.w;
      #pragma unroll
      for (int o = 32; o > 0; o >>= 1) d += __shfl_down(d, o);
    }
    if (lane == 0) salpha[t] = d;
  }
  __syncthreads();
  if (tid < 64) {                        // wave-parallel softmax over <=60 tokens
    int valid = (tid < NT) && svalid[tid];
    float v = valid ? salpha[tid] : -1e30f;
    float m = v;
    #pragma unroll
    for (int o = 32; o > 0; o >>= 1) m = fmaxf(m, __shfl_xor(m, o));
    float e = valid ? expf(v - m) : 0.0f;
    float ssum = e;
    #pragma unroll
    for (int o = 32; o > 0; o >>= 1) ssum += __shfl_xor(ssum, o);
    if (tid < NT) salpha[tid] = e / ssum;
  }
  __syncthreads();
  float acc = 0.0f;
  for (int t = 0; t < NT; t++) {
    float a = salpha[t];
    if (a != 0.0f) acc += a * bf2f(es[t][tid]);
  }
  {
    uint16_t hi = f2bf(acc);
    Xh[tid] = hi; Xl[tid] = f2bf(acc - bf2f(hi));
  }
  if (tid < NF) {
    float fa = 0.0f;
    const float* fp = xfeat + (size_t)bs * NT * NF + tid;
    for (int t = 0; t < NT; t++) if (svalid[t]) fa += fp[t * NF];
    uint16_t hi = f2bf(fa);
    Xh[NH + tid] = hi; Xl[NH + tid] = f2bf(fa - bf2f(hi));
  }
}

// ------- gbase = X @ wih^T + bih + bhh, hi/lo split operands ----------------
__global__ __launch_bounds__(512) void k_gbase(
    const uint16_t* __restrict__ Xb, const uint16_t* __restrict__ wihb,
    const float* __restrict__ bih_f, const float* __restrict__ bhh_f,
    const float* __restrict__ bih_b, const float* __restrict__ bhh_b,
    float* __restrict__ gbase)
{
  const int n = NG * NDIN;
  int wave = threadIdx.x >> 6, lane = threadIdx.x & 63;
  int job = blockIdx.x * 8 + wave;
  int dir = job / 1280;
  int r = job % 1280;
  int nt = r % 64, ms = r / 64;
  int m0 = ms * 64;
  const uint16_t* Wh = wihb + (size_t)dir * n;
  const uint16_t* Wl = Wh + (size_t)2 * n;
  const uint16_t* Ah = Xb;
  const uint16_t* Al = Xb + (size_t)NSB * NDIN;
  int lrow = lane & 15, lk = (lane >> 4) * 8;
  f32x4 acc0 = {0,0,0,0}, acc1 = acc0, acc2 = acc0, acc3 = acc0;
  for (int kk = 0; kk < 10; kk++) {
    int k0 = kk * 32 + lk;
    bfrag bh, bl, ah0, ah1, ah2, ah3, al0, al1, al2, al3;
    bh.q = *(const uint4*)(Wh + (size_t)(nt * 16 + lrow) * NDIN + k0);
    bl.q = *(const uint4*)(Wl + (size_t)(nt * 16 + lrow) * NDIN + k0);
    ah0.q = *(const uint4*)(Ah + (size_t)(m0 +  0 + lrow) * NDIN + k0);
    ah1.q = *(const uint4*)(Ah + (size_t)(m0 + 16 + lrow) * NDIN + k0);
    ah2.q = *(const uint4*)(Ah + (size_t)(m0 + 32 + lrow) * NDIN + k0);
    ah3.q = *(const uint4*)(Ah + (size_t)(m0 + 48 + lrow) * NDIN + k0);
    al0.q = *(const uint4*)(Al + (size_t)(m0 +  0 + lrow) * NDIN + k0);
    al1.q = *(const uint4*)(Al + (size_t)(m0 + 16 + lrow) * NDIN + k0);
    al2.q = *(const uint4*)(Al + (size_t)(m0 + 32 + lrow) * NDIN + k0);
    al3.q = *(const uint4*)(Al + (size_t)(m0 + 48 + lrow) * NDIN + k0);
    acc0 = __builtin_amdgcn_mfma_f32_16x16x32_bf16(ah0.v, bh.v, acc0, 0, 0, 0);
    acc0 = __builtin_amdgcn_mfma_f32_16x16x32_bf16(ah0.v, bl.v, acc0, 0, 0, 0);
    acc0 = __builtin_amdgcn_mfma_f32_16x16x32_bf16(al0.v, bh.v, acc0, 0, 0, 0);
    acc1 = __builtin_amdgcn_mfma_f32_16x16x32_bf16(ah1.v, bh.v, acc1, 0, 0, 0);
    acc1 = __builtin_amdgcn_mfma_f32_16x16x32_bf16(ah1.v, bl.v, acc1, 0, 0, 0);
    acc1 = __builtin_amdgcn_mfma_f32_16x16x32_bf16(al1.v, bh.v, acc1, 0, 0, 0);
    acc2 = __builtin_amdgcn_mfma_f32_16x16x32_bf16(ah2.v, bh.v, acc2, 0, 0, 0);
    acc2 = __builtin_amdgcn_mfma_f32_16x16x32_bf16(ah2.v, bl.v, acc2, 0, 0, 0);
    acc2 = __builtin_amdgcn_mfma_f32_16x16x32_bf16(al2.v, bh.v, acc2, 0, 0, 0);
    acc3 = __builtin_amdgcn_mfma_f32_16x16x32_bf16(ah3.v, bh.v, acc3, 0, 0, 0);
    acc3 = __builtin_amdgcn_mfma_f32_16x16x32_bf16(ah3.v, bl.v, acc3, 0, 0, 0);
    acc3 = __builtin_amdgcn_mfma_f32_16x16x32_bf16(al3.v, bh.v, acc3, 0, 0, 0);
  }
  int col = nt * 16 + lrow;
  float bias = dir ? (bih_b[col] + bhh_b[col]) : (bih_f[col] + bhh_f[col]);
  float* gb = gbase + (size_t)dir * NSB * NG;
  int rb = (lane >> 4) * 4;
  #pragma unroll
  for (int rr = 0; rr < 4; rr++) {
    gb[(size_t)(m0 +  0 + rb + rr) * NG + col] = acc0[rr] + bias;
    gb[(size_t)(m0 + 16 + rb + rr) * NG + col] = acc1[rr] + bias;
    gb[(size_t)(m0 + 32 + rb + rr) * NG + col] = acc2[rr] + bias;
    gb[(size_t)(m0 + 48 + rb + rr) * NG + col] = acc3[rr] + bias;
  }
}

// ---------------- persistent bidirectional LSTM: 16 blocks (R12 verbatim) ---
__global__ __launch_bounds__(512, 2) void k_lstm(
    const float* __restrict__ whh_f_, const float* __restrict__ whh_b_,
    const float* __restrict__ gbase, const int* __restrict__ slen,
    uint32_t* __restrict__ gr)
{
  int wg = blockIdx.x;
  int dir = wg >> 3, p = wg & 7;
  int u0 = p * 32;
  int tid = threadIdx.x, wave = tid >> 6, lane = tid & 63;
  int lrow = lane & 15, lkb = (lane >> 4) * 8;
  const float* Wr = dir ? whh_b_ : whh_f_;
  const float* gb = gbase + (size_t)dir * NSB * NG;
  uint32_t* grd = gr + (size_t)dir * 2 * 64 * NB * 4;   // [par][g64][batch]{4xu32}

  __shared__ __attribute__((aligned(16))) uint16_t hs[NB][264];
  __shared__ float tscr[8][32 * 18];

  bfrag wh[8];
  {
    int wr = (lrow >> 2) * 256 + u0 + wave * 4 + (lrow & 3);
    const float* wrow = Wr + (size_t)wr * NH;
    #pragma unroll
    for (int kk = 0; kk < 8; kk++) {
      int k0 = kk * 32 + lkb;
      bfrag th;
      #pragma unroll
      for (int e = 0; e < 8; e++) th.u[e] = f2bf(wrow[k0 + e]);
      wh[kk] = th;
    }
  }
  int beta = lane >> 1;
  int g64 = p * 8 + wave;
  int len = slen[beta];
  uint32_t hprev_hi = 0;
  float c0 = 0.0f, c1 = 0.0f;

  unsigned long long sa[2][4];
  #pragma unroll
  for (int par = 0; par < 2; par++) {
    const uint32_t* gpar = grd + (size_t)par * 64 * NB * 4;
    #pragma unroll
    for (int q = 0; q < 4; q++)
      sa[par][q] = (unsigned long long)(uintptr_t)(gpar + (size_t)(tid + q * 512) * 4);
  }

  for (int i = 0; i < NS; i++) {
    int t = dir ? (NS - 1 - i) : i;
    const float* gptr = gb + ((size_t)t * NB + beta) * NG + u0 + wave * 4 + (lane & 1) * 2;
    f2arr g0, g1, g2, g3;
    g0.v = *(const float2*)(gptr);
    g1.v = *(const float2*)(gptr + 256);
    g2.v = *(const float2*)(gptr + 512);
    g3.v = *(const float2*)(gptr + 768);
    u32x4 v0, v1, v2, v3;
    {
      const unsigned long long* a = sa[i & 1];
      uint32_t need = (uint32_t)i;
      long spins = 0;
      for (;;) {
        asm volatile(
          "global_load_dwordx4 %0, %4, off sc1\n\t"
          "global_load_dwordx4 %1, %5, off sc1\n\t"
          "global_load_dwordx4 %2, %6, off sc1\n\t"
          "global_load_dwordx4 %3, %7, off sc1\n\t"
          "s_waitcnt vmcnt(0)"
          : "=&v"(v0), "=&v"(v1), "=&v"(v2), "=&v"(v3)
          : "v"(a[0]), "v"(a[1]), "v"(a[2]), "v"(a[3])
          : "memory");
        if (v0.x >= need && v1.x >= need && v2.x >= need && v3.x >= need) break;
        if (++spins > (1L << 16)) break;
      }
    }
    __syncthreads();
    #pragma unroll
    for (int q = 0; q < 4; q++) {
      int s = tid + q * 512;
      int gq = s >> 5, bb = s & 31;
      u32x4 vv = (q == 0) ? v0 : (q == 1) ? v1 : (q == 2) ? v2 : v3;
      uint32_t* d = (uint32_t*)(&hs[bb][gq * 4]);
      d[0] = vv.y; d[1] = vv.z;
    }
    __syncthreads();
    f32x4 acc0 = {0,0,0,0}, acc1 = acc0;
    #pragma unroll
    for (int kk = 0; kk < 8; kk++) {
      int k0 = kk * 32 + lkb;
      bfrag ah0, ah1;
      ah0.q = *(const uint4*)(&hs[lrow][k0]);
      ah1.q = *(const uint4*)(&hs[16 + lrow][k0]);
      acc0 = __builtin_amdgcn_mfma_f32_16x16x32_bf16(ah0.v, wh[kk].v, acc0, 0, 0, 0);
      acc1 = __builtin_amdgcn_mfma_f32_16x16x32_bf16(ah1.v, wh[kk].v, acc1, 0, 0, 0);
    }
    volatile float* ts = &tscr[wave][0];
    {
      int colT = lane & 15, rb = (lane >> 4) * 4;
      #pragma unroll
      for (int rr = 0; rr < 4; rr++) {
        ts[(rb + rr) * 18 + colT]      = acc0[rr];
        ts[(16 + rb + rr) * 18 + colT] = acc1[rr];
      }
    }
    int e2 = (lane & 1) * 2;
    float gv00 = ts[beta * 18 + 0 + e2],  gv01 = ts[beta * 18 + 1 + e2];
    float gv10 = ts[beta * 18 + 4 + e2],  gv11 = ts[beta * 18 + 5 + e2];
    float gv20 = ts[beta * 18 + 8 + e2],  gv21 = ts[beta * 18 + 9 + e2];
    float gv30 = ts[beta * 18 + 12 + e2], gv31 = ts[beta * 18 + 13 + e2];
    {
      int upd = (t < len) ? 1 : 0;
      float gi0 = gv00 + g0.a[0], gi1 = gv01 + g0.a[1];
      float gf0 = gv10 + g1.a[0], gf1 = gv11 + g1.a[1];
      float gg0 = gv20 + g2.a[0], gg1 = gv21 + g2.a[1];
      float go0 = gv30 + g3.a[0], go1 = gv31 + g3.a[1];
      float c2a = sig_fast(gf0) * c0 + sig_fast(gi0) * tanh_fast(gg0);
      float c2b = sig_fast(gf1) * c1 + sig_fast(gi1) * tanh_fast(gg1);
      float h2a = sig_fast(go0) * tanh_fast(c2a);
      float h2b = sig_fast(go1) * tanh_fast(c2b);
      c0 = upd ? c2a : c0;
      c1 = upd ? c2b : c1;
      uint32_t hiw;
      if (upd) {
        uint16_t ha = f2bf(h2a), hbb = f2bf(h2b);
        hiw = (uint32_t)ha | ((uint32_t)hbb << 16);
      } else hiw = hprev_hi;
      hprev_hi = hiw;
      uint32_t hiw_p = __shfl_down(hiw, 1);
      if ((lane & 1) == 0) {
        uint32_t* gout = grd + ((size_t)(((i + 1) & 1) * 64 + g64) * NB + beta) * 4;
        u32x4 pv;
        pv.x = (uint32_t)(i + 1); pv.y = hiw; pv.z = hiw_p; pv.w = 0u;
        asm volatile("global_store_dwordx4 %0, %1, off sc1"
                     :: "v"((unsigned long long)(uintptr_t)gout), "v"(pv) : "memory");
      }
    }
  }
}

// ------- FC + BatchNorm + ReLU + log_softmax(axis=0): 16 blocks, wave/unit --
__global__ __launch_bounds__(512) void k_final(
    const uint32_t* __restrict__ gr, const float* __restrict__ fc_w,
    const float* __restrict__ fc_b, const float* __restrict__ gamma_,
    const float* __restrict__ beta_, float* __restrict__ outp)
{
  __shared__ float hid[NB][513];        // +1 pad: BN-phase row reads spread banks
  int tid = threadIdx.x;
  // decode granules (parity 0, NS even): {tag, hi_pair0, hi_pair1, pad}
  for (int idx = tid; idx < NB * 512; idx += 512) {
    int bb = idx >> 9, k = idx & 511;
    int bsrc = 2 * (bb & 15) + (k >> 8);
    int hcol = k & 255;
    int dirn = (bb < 16) ? 0 : 1;
    const uint32_t* g = gr + ((size_t)dirn * 2 * 64 * NB + (size_t)(hcol >> 2) * NB + bsrc) * 4;
    uint32_t w = ld_agent_u32(g + 1 + ((hcol >> 1) & 1));
    hid[bb][k] = bf2f((uint16_t)(w >> ((hcol & 1) * 16)));
  }
  __syncthreads();
  int wv = tid >> 6, lane = tid & 63;
  int o = blockIdx.x * 8 + wv;          // 16 blocks x 8 units = 128
  int b = lane >> 1, half = lane & 1;
  const float* wrow = fc_w + (size_t)o * 512 + half * 256;
  const float* hrow = &hid[b][half * 256];
  float part = 0.0f;
  #pragma unroll 8
  for (int j = 0; j < 256; j++) part += wrow[j] * hrow[j];
  part += __shfl_xor(part, 1);          // both lanes of pair hold full dot
  float y = part + fc_b[o];
  // BN over batch: butterfly over bits 1..5 sums each b exactly once per lane
  float s = y;
  #pragma unroll
  for (int off = 2; off < 64; off <<= 1) s += __shfl_xor(s, off);
  float mu = s * (1.0f / 32.0f);
  float d = y - mu;
  float v2 = d * d;
  #pragma unroll
  for (int off = 2; off < 64; off <<= 1) v2 += __shfl_xor(v2, off);
  float var = v2 * (1.0f / 32.0f);
  float gm = gamma_[o], be = beta_[o];
  float inv = 1.0f / sqrtf(var + 1e-5f);
  float yy = fmaxf(gm * (y - mu) * inv + be, 0.0f);
  float m = yy;
  #pragma unroll
  for (int off = 2; off < 64; off <<= 1) m = fmaxf(m, __shfl_xor(m, off));
  float e = expf(yy - m);
  float se = e;
  #pragma unroll
  for (int off = 2; off < 64; off <<= 1) se += __shfl_xor(se, off);
  float lse = m + logf(se);
  if (half == 0) outp[b * NOUT + o] = yy - lse;
}

extern "C" void kernel_launch(void* const* d_in, const int* in_sizes, int n_in,
                              void* d_out, int out_size, void* d_ws, size_t ws_size,
                              hipStream_t stream) {
  (void)in_sizes; (void)n_in; (void)out_size; (void)ws_size;
  const int*   x      = (const int*)  d_in[0];
  const void*  xmask  =               d_in[1];
  const float* xfeat  = (const float*)d_in[2];
  const int*   slen   = (const int*)  d_in[3];
  const float* emb    = (const float*)d_in[6];
  const float* attn_w = (const float*)d_in[7];
  const float* wih_f  = (const float*)d_in[9];
  const float* whh_f  = (const float*)d_in[10];
  const float* bih_f  = (const float*)d_in[11];
  const float* bhh_f  = (const float*)d_in[12];
  const float* wih_b  = (const float*)d_in[13];
  const float* whh_b  = (const float*)d_in[14];
  const float* bih_b  = (const float*)d_in[15];
  const float* bhh_b  = (const float*)d_in[16];
  const float* fc_w   = (const float*)d_in[17];
  const float* fc_b   = (const float*)d_in[18];
  const float* gam    = (const float*)d_in[19];
  const float* bet    = (const float*)d_in[20];

  char* ws = (char*)d_ws;
  int*      flags = (int*)ws;                        // slots [8..40): per-block detect
  uint32_t* gr    = (uint32_t*)(ws + 4096);          // granules 2dir x 2par x 64 x 32 x 16B (131,072 B)
  uint16_t* Xb    = (uint16_t*)(ws + 135168);        // 2 planes x 1280x320 bf16 (1,638,400 B)
  uint16_t* wihb  = (uint16_t*)(ws + 1773568);       // 4 planes x 1024x320 bf16 (2,621,440 B)
  float*    gbase = (float*)(ws + 4395008);          // 2x1280x1024 f32 (10,485,760 B)

  k_detect<<<32, 256, 0, stream>>>((const uint32_t*)xmask, flags, gr);
  k_attn_prep<<<2560, 256, 0, stream>>>(x, xmask, xfeat, slen, emb, attn_w, Xb, flags,
                                        wih_f, wih_b, wihb);
  k_gbase<<<320, 512, 0, stream>>>(Xb, wihb, bih_f, bhh_f, bih_b, bhh_b, gbase);
  k_lstm<<<16, 512, 0, stream>>>(whh_f, whh_b, gbase, slen, gr);
  k_final<<<16, 512, 0, stream>>>(gr, fc_w, fc_b, gam, bet, (float*)d_out);
}